// Round 12
// baseline (290.087 us; speedup 1.0000x reference)
//
#include <hip/hip_runtime.h>

#define NNODES 50000
#define NEDGES 800000
#define SCAN_BLOCKS ((NNODES + 255) / 256)   // 196
#define NPART (NNODES / 8)                   // 6250 nodes per XCD partition
#define EPS 2048                             // edges per slice
#define NSLICE ((NEDGES + EPS - 1) / EPS)    // 391

// per-edge attention weights: softmax over heads of (s_src - s_dst + c)
__device__ __forceinline__ float4 softq(float4 ss, float4 sd, float4 c4) {
  float l0 = ss.x - sd.x + c4.x;
  float l1 = ss.y - sd.y + c4.y;
  float l2 = ss.z - sd.z + c4.z;
  float l3 = ss.w - sd.w + c4.w;
  float mx = fmaxf(fmaxf(l0, l1), fmaxf(l2, l3));
  float e0 = __expf(l0 - mx), e1 = __expf(l1 - mx);
  float e2 = __expf(l2 - mx), e3 = __expf(l3 - mx);
  float inv = 1.f / (e0 + e1 + e2 + e3);
  return make_float4(e0 * inv, e1 * inv, e2 * inv, e3 * inv);
}

// ---------------- CSR build: histogram over dst + per-edge rank ----------------
__global__ __launch_bounds__(256) void hist_kernel(const int* __restrict__ ei,
                                                   int* __restrict__ counts,
                                                   int* __restrict__ rank) {
  int e = blockIdx.x * 256 + threadIdx.x;
  if (e < NEDGES) rank[e] = atomicAdd(&counts[ei[NEDGES + e]], 1);
}

__global__ __launch_bounds__(256) void scanA_kernel(const int* __restrict__ counts,
                                                    int* __restrict__ rowptr,
                                                    int* __restrict__ blockSum) {
  __shared__ int sm[256];
  int i = blockIdx.x * 256 + threadIdx.x;
  int v = (i < NNODES) ? counts[i] : 0;
  sm[threadIdx.x] = v;
  __syncthreads();
  for (int off = 1; off < 256; off <<= 1) {
    int x = (threadIdx.x >= off) ? sm[threadIdx.x - off] : 0;
    __syncthreads();
    sm[threadIdx.x] += x;
    __syncthreads();
  }
  if (i < NNODES) rowptr[i] = sm[threadIdx.x] - v;
  if (threadIdx.x == 255) blockSum[blockIdx.x] = sm[255];
}

__global__ __launch_bounds__(256) void scanB_kernel(int* __restrict__ blockSum,
                                                    int* __restrict__ blockOff) {
  __shared__ int sm[256];
  int v = (threadIdx.x < SCAN_BLOCKS) ? blockSum[threadIdx.x] : 0;
  sm[threadIdx.x] = v;
  __syncthreads();
  for (int off = 1; off < 256; off <<= 1) {
    int x = (threadIdx.x >= off) ? sm[threadIdx.x - off] : 0;
    __syncthreads();
    sm[threadIdx.x] += x;
    __syncthreads();
  }
  if (threadIdx.x < SCAN_BLOCKS) blockOff[threadIdx.x] = sm[threadIdx.x] - v;
}

__global__ __launch_bounds__(256) void scanC_kernel(int* __restrict__ rowptr,
                                                    const int* __restrict__ blockOff) {
  int i = blockIdx.x * 256 + threadIdx.x;
  if (i < NNODES) rowptr[i] += blockOff[blockIdx.x];
  if (i == 0) rowptr[NNODES] = NEDGES;
}

// Atomic-free XCD-partitioned scatter.
__global__ __launch_bounds__(256) void scatter_kernel(const int* __restrict__ ei,
                                                      const int* __restrict__ rowptr,
                                                      const int* __restrict__ rank,
                                                      int* __restrict__ col) {
  const int p = blockIdx.x & 7;
  const int sl = blockIdx.x >> 3;
  const int P0 = p * NPART;
  const int e1 = min((sl + 1) * EPS, NEDGES);
  for (int e = sl * EPS + threadIdx.x; e < e1; e += 256) {
    int dst = __builtin_nontemporal_load(&ei[NEDGES + e]);
    if ((unsigned)(dst - P0) < (unsigned)NPART) {
      int pos = rowptr[dst] + __builtin_nontemporal_load(&rank[e]);
      col[pos] = __builtin_nontemporal_load(&ei[e]);
    }
  }
}

// ---------------- W pre-transpose into [k][o] rows (scalar-load friendly) ----
__global__ __launch_bounds__(256) void prep_kernel(const float* __restrict__ W1,
                                                   const float* __restrict__ W2,
                                                   const float* __restrict__ W3,
                                                   float* __restrict__ Wk1,
                                                   float* __restrict__ Wk2,
                                                   float* __restrict__ Wk3) {
  int i = blockIdx.x * 256 + threadIdx.x;
  if (i < 4096) {
    int f = i >> 6, j = i & 63;
    Wk1[i] = W1[f * 64 + ((j & 3) << 4) + (j >> 2)];
  } else if (i < 6144) {
    int i2 = i - 4096;
    int k = i2 >> 5, o = i2 & 31;
    int hh = k >> 4, f = k & 15;
    Wk2[i2] = W2[f * 128 + hh * 32 + o];
  } else if (i < 14336) {
    int i3 = i - 6144;
    int k = i3 >> 6, o = i3 & 63;
    int hh = k >> 5, f = k & 31;
    Wk3[i3] = W3[f * 256 + hh * 64 + o];
  }
}

// ---------------- per-node GEMM: C[n][o] = A[n][:K] . W[o][:K] ----------------
// A-tile staged TRANSPOSED in LDS; per-k: 1 conflict-free ds_read_b32 + MO FMA
// with W on the scalar path (wave-uniform o0 -> s_load). VALU-bound (round 11).
template<int K, int OUTT, int MO, bool DEGBIAS>
__global__ __launch_bounds__(256) void ngemm_kernel(const float* __restrict__ A,
                                                    const float* __restrict__ Wk,
                                                    const int* __restrict__ rowptr,
                                                    const float* __restrict__ bptr,
                                                    float* __restrict__ C) {
  constexpr int OG = OUTT / MO;
  constexpr int NB = 256 / OG;
  constexpr int NBp = NB + 1;
  __shared__ float ldsT[K * NBp];
  const int tid = threadIdx.x;
  const int nb0 = blockIdx.x * NB;
  for (int i = tid; i < NB * (K / 4); i += 256) {
    int r = i / (K / 4), kq = i - r * (K / 4);
    int n = nb0 + r;
    if (n >= NNODES) n = NNODES - 1;
    float4 v = *(const float4*)(A + (size_t)n * K + (kq << 2));
    ldsT[((kq << 2) + 0) * NBp + r] = v.x;
    ldsT[((kq << 2) + 1) * NBp + r] = v.y;
    ldsT[((kq << 2) + 2) * NBp + r] = v.z;
    ldsT[((kq << 2) + 3) * NBp + r] = v.w;
  }
  __syncthreads();
  const int o0 = __builtin_amdgcn_readfirstlane(tid / NB) * MO;
  const int nl = tid & (NB - 1);
  const int n = nb0 + nl;
  float acc[MO];
#pragma unroll
  for (int m = 0; m < MO; ++m) acc[m] = 0.f;
#pragma unroll 4
  for (int k = 0; k < K; ++k) {
    float a = ldsT[k * NBp + nl];
    const float* wr = Wk + k * OUTT + o0;   // wave-uniform -> s_load
#pragma unroll
    for (int m = 0; m < MO; ++m) acc[m] += a * wr[m];
  }
  if (n < NNODES) {
    float sc = 1.f;
    if (DEGBIAS) sc = 1.f / (float)(rowptr[n + 1] - rowptr[n] + 1);
#pragma unroll
    for (int m4 = 0; m4 < MO / 4; ++m4) {
      float4 v;
      if (DEGBIAS) {
        v.x = fmaxf(acc[m4 * 4 + 0] * sc + bptr[o0 + m4 * 4 + 0], 0.f);
        v.y = fmaxf(acc[m4 * 4 + 1] * sc + bptr[o0 + m4 * 4 + 1], 0.f);
        v.z = fmaxf(acc[m4 * 4 + 2] * sc + bptr[o0 + m4 * 4 + 2], 0.f);
        v.w = fmaxf(acc[m4 * 4 + 3] * sc + bptr[o0 + m4 * 4 + 3], 0.f);
      } else {
        v = make_float4(acc[m4 * 4 + 0], acc[m4 * 4 + 1],
                        acc[m4 * 4 + 2], acc[m4 * 4 + 3]);
      }
      *(float4*)(C + (size_t)n * OUTT + o0 + m4 * 4) = v;
    }
  }
}

// ---------------- s = x @ u  ([N,4]) ----------------
template<int FIN>
__global__ __launch_bounds__(256) void s_kernel(const float* __restrict__ x,
                                                const float* __restrict__ u,
                                                float* __restrict__ s) {
  int tid = blockIdx.x * 256 + threadIdx.x;
  int n = tid >> 2, h = tid & 3;
  if (n >= NNODES) return;
  const float4* xr = (const float4*)(x + (size_t)n * FIN);
  float acc = 0.f;
#pragma unroll
  for (int f4 = 0; f4 < FIN / 4; ++f4) {
    float4 xv = xr[f4];
    acc += xv.x * u[(4 * f4 + 0) * 4 + h] + xv.y * u[(4 * f4 + 1) * 4 + h] +
           xv.z * u[(4 * f4 + 2) * 4 + h] + xv.w * u[(4 * f4 + 3) * 4 + h];
  }
  s[tid] = acc;  // tid == n*4+h
}

// ---------------- layer-1 gather over t, softmax fused (16 lanes/node, 4x) ----
__global__ __launch_bounds__(256) void gather1_kernel(const int* __restrict__ rowptr,
                                                      const int* __restrict__ col,
                                                      const float* __restrict__ s,
                                                      const float* __restrict__ t,
                                                      const float* __restrict__ cptr,
                                                      const float* __restrict__ bptr,
                                                      float* __restrict__ h) {
  const int lane = threadIdx.x & 15;
  const int sub = threadIdx.x >> 4;
  const int n = blockIdx.x * 16 + sub;
  if (n >= NNODES) return;
  float4 c4 = *(const float4*)cptr;
  float mxc = fmaxf(fmaxf(c4.x, c4.y), fmaxf(c4.z, c4.w));
  float qs0 = __expf(c4.x - mxc), qs1 = __expf(c4.y - mxc);
  float qs2 = __expf(c4.z - mxc), qs3 = __expf(c4.w - mxc);
  float sinv = 1.f / (qs0 + qs1 + qs2 + qs3);
  float4 sd = *(const float4*)(s + 4 * (size_t)n);
  float4 tv = *((const float4*)(t + (size_t)n * 64) + lane);
  float acc = (qs0 * tv.x + qs1 * tv.y + qs2 * tv.z + qs3 * tv.w) * sinv;
  const int beg = rowptr[n], end = rowptr[n + 1];
  int idx = beg;
  for (; idx + 3 < end; idx += 4) {
    int s0 = col[idx], s1 = col[idx + 1], s2 = col[idx + 2], s3 = col[idx + 3];
    float4 a0 = *(const float4*)(s + 4 * (size_t)s0);
    float4 a1 = *(const float4*)(s + 4 * (size_t)s1);
    float4 a2 = *(const float4*)(s + 4 * (size_t)s2);
    float4 a3 = *(const float4*)(s + 4 * (size_t)s3);
    float4 t0 = *((const float4*)(t + (size_t)s0 * 64) + lane);
    float4 t1 = *((const float4*)(t + (size_t)s1 * 64) + lane);
    float4 t2 = *((const float4*)(t + (size_t)s2 * 64) + lane);
    float4 t3 = *((const float4*)(t + (size_t)s3 * 64) + lane);
    float4 q0 = softq(a0, sd, c4);
    float4 q1 = softq(a1, sd, c4);
    float4 q2 = softq(a2, sd, c4);
    float4 q3 = softq(a3, sd, c4);
    acc += q0.x * t0.x + q0.y * t0.y + q0.z * t0.z + q0.w * t0.w;
    acc += q1.x * t1.x + q1.y * t1.y + q1.z * t1.z + q1.w * t1.w;
    acc += q2.x * t2.x + q2.y * t2.y + q2.z * t2.z + q2.w * t2.w;
    acc += q3.x * t3.x + q3.y * t3.y + q3.z * t3.z + q3.w * t3.w;
  }
  for (; idx < end; ++idx) {
    int src = col[idx];
    float4 qv = softq(*(const float4*)(s + 4 * (size_t)src), sd, c4);
    float4 tw = *((const float4*)(t + (size_t)src * 64) + lane);
    acc += qv.x * tw.x + qv.y * tw.y + qv.z * tw.z + qv.w * tw.w;
  }
  float d = (float)(end - beg + 1);
  h[(size_t)n * 16 + lane] = fmaxf(acc / d + bptr[lane], 0.f);
}

// ---------------- g-gather, softmax fused: g[n][h][f] = sum_j q_jh x_j[f] ----
template<int FIN>
__global__ __launch_bounds__(256) void gatherG_kernel(const int* __restrict__ rowptr,
                                                      const int* __restrict__ col,
                                                      const float* __restrict__ s,
                                                      const float* __restrict__ x,
                                                      const float* __restrict__ cptr,
                                                      float* __restrict__ g) {
  constexpr int NSUB = 256 / FIN;
  const int f = threadIdx.x & (FIN - 1);
  const int sub = threadIdx.x / FIN;
  const int n = blockIdx.x * NSUB + sub;
  if (n >= NNODES) return;
  float4 c4 = *(const float4*)cptr;
  float mxc = fmaxf(fmaxf(c4.x, c4.y), fmaxf(c4.z, c4.w));
  float qs0 = __expf(c4.x - mxc), qs1 = __expf(c4.y - mxc);
  float qs2 = __expf(c4.z - mxc), qs3 = __expf(c4.w - mxc);
  float sinv = 1.f / (qs0 + qs1 + qs2 + qs3);
  float4 sd = *(const float4*)(s + 4 * (size_t)n);
  float xn = x[(size_t)n * FIN + f];
  float g0 = qs0 * sinv * xn, g1 = qs1 * sinv * xn;
  float g2 = qs2 * sinv * xn, g3 = qs3 * sinv * xn;
  const int beg = rowptr[n], end = rowptr[n + 1];
  int idx = beg;
  for (; idx + 3 < end; idx += 4) {
    int s0 = col[idx], s1 = col[idx + 1], s2 = col[idx + 2], s3 = col[idx + 3];
    float4 a0 = *(const float4*)(s + 4 * (size_t)s0);
    float4 a1 = *(const float4*)(s + 4 * (size_t)s1);
    float4 a2 = *(const float4*)(s + 4 * (size_t)s2);
    float4 a3 = *(const float4*)(s + 4 * (size_t)s3);
    float x0 = x[(size_t)s0 * FIN + f];
    float x1 = x[(size_t)s1 * FIN + f];
    float x2 = x[(size_t)s2 * FIN + f];
    float x3 = x[(size_t)s3 * FIN + f];
    float4 q0 = softq(a0, sd, c4);
    float4 q1 = softq(a1, sd, c4);
    float4 q2 = softq(a2, sd, c4);
    float4 q3 = softq(a3, sd, c4);
    g0 += q0.x * x0 + q1.x * x1 + q2.x * x2 + q3.x * x3;
    g1 += q0.y * x0 + q1.y * x1 + q2.y * x2 + q3.y * x3;
    g2 += q0.z * x0 + q1.z * x1 + q2.z * x2 + q3.z * x3;
    g3 += q0.w * x0 + q1.w * x1 + q2.w * x2 + q3.w * x3;
  }
  for (; idx < end; ++idx) {
    int src = col[idx];
    float4 qv = softq(*(const float4*)(s + 4 * (size_t)src), sd, c4);
    float xv = x[(size_t)src * FIN + f];
    g0 += qv.x * xv; g1 += qv.y * xv; g2 += qv.z * xv; g3 += qv.w * xv;
  }
  float* gr = g + (size_t)n * 4 * FIN;
  gr[0 * FIN + f] = g0;
  gr[1 * FIN + f] = g1;
  gr[2 * FIN + f] = g2;
  gr[3 * FIN + f] = g3;
}

// ---------------- BN batch-stats over h3 [N,64] ----------------
__global__ __launch_bounds__(256) void stats_kernel(const float* __restrict__ h3,
                                                    float* __restrict__ sums) {
  const int o = threadIdx.x & 63;
  const int r = threadIdx.x >> 6;
  float accS = 0.f, accQ = 0.f;
  for (int base = blockIdx.x * 4; base < NNODES; base += gridDim.x * 4) {
    int n = base + r;
    if (n < NNODES) {
      float v = h3[(size_t)n * 64 + o];
      accS += v;
      accQ += v * v;
    }
  }
  __shared__ float ls[256], lq[256];
  ls[threadIdx.x] = accS;
  lq[threadIdx.x] = accQ;
  __syncthreads();
  if (threadIdx.x < 64) {
    float a = ls[threadIdx.x] + ls[threadIdx.x + 64] + ls[threadIdx.x + 128] + ls[threadIdx.x + 192];
    float qq = lq[threadIdx.x] + lq[threadIdx.x + 64] + lq[threadIdx.x + 128] + lq[threadIdx.x + 192];
    atomicAdd(&sums[threadIdx.x], a);
    atomicAdd(&sums[64 + threadIdx.x], qq);
  }
}

// ---------------- BN + MLP head + sigmoid, one thread per node ----------------
__global__ __launch_bounds__(256) void mlp_kernel(
    const float* __restrict__ h3, const float* __restrict__ sums,
    const float* __restrict__ gamma, const float* __restrict__ beta,
    const float* __restrict__ lw1, const float* __restrict__ lb1,
    const float* __restrict__ lw2, const float* __restrict__ lb2,
    const float* __restrict__ lw3, const float* __restrict__ lb3,
    const float* __restrict__ lw4, const float* __restrict__ lb4,
    const float* __restrict__ ow, const float* __restrict__ ob,
    float* __restrict__ out) {
  __shared__ float w1[64 * 32], w2[32 * 16], w3[16 * 8], w4[8 * 4];
  __shared__ float b1s[32], b2s[16], b3s[8], b4s[4], wos[4];
  __shared__ float scale[64], shift[64];
  int tid = threadIdx.x;
  for (int i = tid; i < 64 * 32; i += 256) w1[i] = lw1[i];
  for (int i = tid; i < 32 * 16; i += 256) w2[i] = lw2[i];
  if (tid < 128) w3[tid] = lw3[tid];
  if (tid < 32) { w4[tid] = lw4[tid]; b1s[tid] = lb1[tid]; }
  if (tid < 16) b2s[tid] = lb2[tid];
  if (tid < 8) b3s[tid] = lb3[tid];
  if (tid < 4) { b4s[tid] = lb4[tid]; wos[tid] = ow[tid]; }
  if (tid < 64) {
    float mu = sums[tid] * (1.f / NNODES);
    float var = sums[64 + tid] * (1.f / NNODES) - mu * mu;
    float sc = rsqrtf(var + 1e-5f) * gamma[tid];
    scale[tid] = sc;
    shift[tid] = beta[tid] - mu * sc;
  }
  __syncthreads();
  int n = blockIdx.x * 256 + tid;
  if (n >= NNODES) return;
  float obv = ob[0];
  const float4* hr = (const float4*)(h3 + (size_t)n * 64);
  float z1[32];
#pragma unroll
  for (int j = 0; j < 32; ++j) z1[j] = b1s[j];
  for (int i4 = 0; i4 < 16; ++i4) {
    float4 hv = hr[i4];
    float a0 = hv.x * scale[4 * i4 + 0] + shift[4 * i4 + 0];
    float a1 = hv.y * scale[4 * i4 + 1] + shift[4 * i4 + 1];
    float a2 = hv.z * scale[4 * i4 + 2] + shift[4 * i4 + 2];
    float a3 = hv.w * scale[4 * i4 + 3] + shift[4 * i4 + 3];
#pragma unroll
    for (int j = 0; j < 32; ++j) {
      z1[j] += a0 * w1[(4 * i4 + 0) * 32 + j] + a1 * w1[(4 * i4 + 1) * 32 + j] +
               a2 * w1[(4 * i4 + 2) * 32 + j] + a3 * w1[(4 * i4 + 3) * 32 + j];
    }
  }
  float z2[16];
#pragma unroll
  for (int j = 0; j < 16; ++j) z2[j] = b2s[j];
  for (int i = 0; i < 32; ++i) {
    float a = fmaxf(z1[i], 0.f);
#pragma unroll
    for (int j = 0; j < 16; ++j) z2[j] += a * w2[i * 16 + j];
  }
  float z3[8];
#pragma unroll
  for (int j = 0; j < 8; ++j) z3[j] = b3s[j];
  for (int i = 0; i < 16; ++i) {
    float a = fmaxf(z2[i], 0.f);
#pragma unroll
    for (int j = 0; j < 8; ++j) z3[j] += a * w3[i * 8 + j];
  }
  float z4[4];
#pragma unroll
  for (int j = 0; j < 4; ++j) z4[j] = b4s[j];
  for (int i = 0; i < 8; ++i) {
    float a = fmaxf(z3[i], 0.f);
#pragma unroll
    for (int j = 0; j < 4; ++j) z4[j] += a * w4[i * 4 + j];
  }
  float zo = obv;
#pragma unroll
  for (int i = 0; i < 4; ++i) zo += fmaxf(z4[i], 0.f) * wos[i];
  out[n] = 1.f / (1.f + __expf(-zo));
}

extern "C" void kernel_launch(void* const* d_in, const int* in_sizes, int n_in,
                              void* d_out, int out_size, void* d_ws, size_t ws_size,
                              hipStream_t stream) {
  const float* x  = (const float*)d_in[0];
  const int*   ei = (const int*)d_in[1];
  const float* W1 = (const float*)d_in[2];  const float* u1 = (const float*)d_in[3];
  const float* c1 = (const float*)d_in[4];  const float* b1 = (const float*)d_in[5];
  const float* W2 = (const float*)d_in[6];  const float* u2 = (const float*)d_in[7];
  const float* c2 = (const float*)d_in[8];  const float* b2 = (const float*)d_in[9];
  const float* W3 = (const float*)d_in[10]; const float* u3 = (const float*)d_in[11];
  const float* c3 = (const float*)d_in[12]; const float* b3 = (const float*)d_in[13];
  const float* gamma = (const float*)d_in[14]; const float* beta = (const float*)d_in[15];
  const float* lw1 = (const float*)d_in[16]; const float* lb1 = (const float*)d_in[17];
  const float* lw2 = (const float*)d_in[18]; const float* lb2 = (const float*)d_in[19];
  const float* lw3 = (const float*)d_in[20]; const float* lb3 = (const float*)d_in[21];
  const float* lw4 = (const float*)d_in[22]; const float* lb4 = (const float*)d_in[23];
  const float* ow  = (const float*)d_in[24]; const float* ob  = (const float*)d_in[25];
  float* out = (float*)d_out;

  float* t    = (float*)d_ws;                         // N*64   (layer-1 t)
  float* g    = t + (size_t)NNODES * 64;              // N*128  (g buffer, max 4*32)
  float* hA   = g + (size_t)NNODES * 128;             // N*64
  float* hB   = hA + (size_t)NNODES * 64;             // N*64
  float* s    = hB + (size_t)NNODES * 64;             // N*4
  float* sums = s + (size_t)NNODES * 4;               // 128
  float* Wk1  = sums + 128;                           // 4096
  float* Wk2  = Wk1 + 4096;                           // 2048
  float* Wk3  = Wk2 + 2048;                           // 8192
  int*   rowptr   = (int*)(Wk3 + 8192);               // N+1 (pad 8)
  int*   counts   = rowptr + NNODES + 8;              // N
  int*   blockSum = counts + NNODES;                  // 256
  int*   blockOff = blockSum + 256;                   // 256
  int*   col      = blockOff + 256;                   // E
  int*   rank     = col + NEDGES;                     // E

  hipMemsetAsync(counts, 0, NNODES * sizeof(int), stream);
  hipMemsetAsync(sums, 0, 128 * sizeof(float), stream);

  // ---- W transposes + CSR by dst ----
  prep_kernel<<<56, 256, 0, stream>>>(W1, W2, W3, Wk1, Wk2, Wk3);
  hist_kernel<<<(NEDGES + 255) / 256, 256, 0, stream>>>(ei, counts, rank);
  scanA_kernel<<<SCAN_BLOCKS, 256, 0, stream>>>(counts, rowptr, blockSum);
  scanB_kernel<<<1, 256, 0, stream>>>(blockSum, blockOff);
  scanC_kernel<<<SCAN_BLOCKS, 256, 0, stream>>>(rowptr, blockOff);
  scatter_kernel<<<NSLICE * 8, 256, 0, stream>>>(ei, rowptr, rank, col);

  // ---- layer 1: 64 -> 16 (t-gather, fused softmax) ----
  ngemm_kernel<64, 64, 16, false><<<(NNODES + 63) / 64, 256, 0, stream>>>(x, Wk1, nullptr, nullptr, t);
  s_kernel<64><<<(NNODES * 4 + 255) / 256, 256, 0, stream>>>(x, u1, s);
  gather1_kernel<<<(NNODES + 15) / 16, 256, 0, stream>>>(rowptr, col, s, t, c1, b1, hA);

  // ---- layer 2: 16 -> 32 (g-gather, fused softmax) ----
  s_kernel<16><<<(NNODES * 4 + 255) / 256, 256, 0, stream>>>(hA, u2, s);
  gatherG_kernel<16><<<(NNODES + 15) / 16, 256, 0, stream>>>(rowptr, col, s, hA, c2, g);
  ngemm_kernel<64, 32, 16, true><<<(NNODES + 127) / 128, 256, 0, stream>>>(g, Wk2, rowptr, b2, hB);

  // ---- layer 3: 32 -> 64 (g-gather, fused softmax) ----
  s_kernel<32><<<(NNODES * 4 + 255) / 256, 256, 0, stream>>>(hB, u3, s);
  gatherG_kernel<32><<<(NNODES + 7) / 8, 256, 0, stream>>>(rowptr, col, s, hB, c3, g);
  ngemm_kernel<128, 64, 16, true><<<(NNODES + 63) / 64, 256, 0, stream>>>(g, Wk3, rowptr, b3, hA);

  // ---- BN stats + MLP head ----
  stats_kernel<<<256, 256, 0, stream>>>(hA, sums);
  mlp_kernel<<<(NNODES + 255) / 256, 256, 0, stream>>>(hA, sums, gamma, beta, lw1, lb1,
                                                       lw2, lb2, lw3, lb3, lw4, lb4,
                                                       ow, ob, out);
}

// Round 13
// 266.296 us; speedup vs baseline: 1.0893x; 1.0893x over previous
//
#include <hip/hip_runtime.h>

#define NNODES 50000
#define NEDGES 800000
#define SCAN_BLOCKS ((NNODES + 255) / 256)   // 196
#define NPART (NNODES / 8)                   // 6250 nodes per XCD partition
#define EPS 2048                             // edges per slice
#define NSLICE ((NEDGES + EPS - 1) / EPS)    // 391

// per-edge attention weights: softmax over heads of (s_src - s_dst + c)
__device__ __forceinline__ float4 softq(float4 ss, float4 sd, float4 c4) {
  float l0 = ss.x - sd.x + c4.x;
  float l1 = ss.y - sd.y + c4.y;
  float l2 = ss.z - sd.z + c4.z;
  float l3 = ss.w - sd.w + c4.w;
  float mx = fmaxf(fmaxf(l0, l1), fmaxf(l2, l3));
  float e0 = __expf(l0 - mx), e1 = __expf(l1 - mx);
  float e2 = __expf(l2 - mx), e3 = __expf(l3 - mx);
  float inv = 1.f / (e0 + e1 + e2 + e3);
  return make_float4(e0 * inv, e1 * inv, e2 * inv, e3 * inv);
}

__device__ __forceinline__ void fma4(float4& a, float q, float4 v) {
  a.x += q * v.x; a.y += q * v.y; a.z += q * v.z; a.w += q * v.w;
}
__device__ __forceinline__ float dot4(float4 a, float4 b) {
  return a.x * b.x + a.y * b.y + a.z * b.z + a.w * b.w;
}

// ---------------- CSR build: histogram over dst + per-edge rank ----------------
__global__ __launch_bounds__(256) void hist_kernel(const int* __restrict__ ei,
                                                   int* __restrict__ counts,
                                                   int* __restrict__ rank) {
  int e = blockIdx.x * 256 + threadIdx.x;
  if (e < NEDGES) rank[e] = atomicAdd(&counts[ei[NEDGES + e]], 1);
}

__global__ __launch_bounds__(256) void scanA_kernel(const int* __restrict__ counts,
                                                    int* __restrict__ rowptr,
                                                    int* __restrict__ blockSum) {
  __shared__ int sm[256];
  int i = blockIdx.x * 256 + threadIdx.x;
  int v = (i < NNODES) ? counts[i] : 0;
  sm[threadIdx.x] = v;
  __syncthreads();
  for (int off = 1; off < 256; off <<= 1) {
    int x = (threadIdx.x >= off) ? sm[threadIdx.x - off] : 0;
    __syncthreads();
    sm[threadIdx.x] += x;
    __syncthreads();
  }
  if (i < NNODES) rowptr[i] = sm[threadIdx.x] - v;
  if (threadIdx.x == 255) blockSum[blockIdx.x] = sm[255];
}

__global__ __launch_bounds__(256) void scanB_kernel(int* __restrict__ blockSum,
                                                    int* __restrict__ blockOff) {
  __shared__ int sm[256];
  int v = (threadIdx.x < SCAN_BLOCKS) ? blockSum[threadIdx.x] : 0;
  sm[threadIdx.x] = v;
  __syncthreads();
  for (int off = 1; off < 256; off <<= 1) {
    int x = (threadIdx.x >= off) ? sm[threadIdx.x - off] : 0;
    __syncthreads();
    sm[threadIdx.x] += x;
    __syncthreads();
  }
  if (threadIdx.x < SCAN_BLOCKS) blockOff[threadIdx.x] = sm[threadIdx.x] - v;
}

__global__ __launch_bounds__(256) void scanC_kernel(int* __restrict__ rowptr,
                                                    const int* __restrict__ blockOff) {
  int i = blockIdx.x * 256 + threadIdx.x;
  if (i < NNODES) rowptr[i] += blockOff[blockIdx.x];
  if (i == 0) rowptr[NNODES] = NEDGES;
}

// Atomic-free XCD-partitioned scatter.
__global__ __launch_bounds__(256) void scatter_kernel(const int* __restrict__ ei,
                                                      const int* __restrict__ rowptr,
                                                      const int* __restrict__ rank,
                                                      int* __restrict__ col) {
  const int p = blockIdx.x & 7;
  const int sl = blockIdx.x >> 3;
  const int P0 = p * NPART;
  const int e1 = min((sl + 1) * EPS, NEDGES);
  for (int e = sl * EPS + threadIdx.x; e < e1; e += 256) {
    int dst = __builtin_nontemporal_load(&ei[NEDGES + e]);
    if ((unsigned)(dst - P0) < (unsigned)NPART) {
      int pos = rowptr[dst] + __builtin_nontemporal_load(&rank[e]);
      col[pos] = __builtin_nontemporal_load(&ei[e]);
    }
  }
}

// ---------------- W pre-transpose into [k][o] rows (scalar-load friendly) ----
__global__ __launch_bounds__(256) void prep_kernel(const float* __restrict__ W1,
                                                   const float* __restrict__ W2,
                                                   const float* __restrict__ W3,
                                                   float* __restrict__ Wk1,
                                                   float* __restrict__ Wk2,
                                                   float* __restrict__ Wk3) {
  int i = blockIdx.x * 256 + threadIdx.x;
  if (i < 4096) {
    int f = i >> 6, j = i & 63;
    Wk1[i] = W1[f * 64 + ((j & 3) << 4) + (j >> 2)];
  } else if (i < 6144) {
    int i2 = i - 4096;
    int k = i2 >> 5, o = i2 & 31;
    int hh = k >> 4, f = k & 15;
    Wk2[i2] = W2[f * 128 + hh * 32 + o];
  } else if (i < 14336) {
    int i3 = i - 6144;
    int k = i3 >> 6, o = i3 & 63;
    int hh = k >> 5, f = k & 31;
    Wk3[i3] = W3[f * 256 + hh * 64 + o];
  }
}

// ---------------- per-node GEMM: C[n][o] = A[n][:K] . W[o][:K] ----------------
template<int K, int OUTT, int MO, bool DEGBIAS>
__global__ __launch_bounds__(256) void ngemm_kernel(const float* __restrict__ A,
                                                    const float* __restrict__ Wk,
                                                    const int* __restrict__ rowptr,
                                                    const float* __restrict__ bptr,
                                                    float* __restrict__ C) {
  constexpr int OG = OUTT / MO;
  constexpr int NB = 256 / OG;
  constexpr int NBp = NB + 1;
  __shared__ float ldsT[K * NBp];
  const int tid = threadIdx.x;
  const int nb0 = blockIdx.x * NB;
  for (int i = tid; i < NB * (K / 4); i += 256) {
    int r = i / (K / 4), kq = i - r * (K / 4);
    int n = nb0 + r;
    if (n >= NNODES) n = NNODES - 1;
    float4 v = *(const float4*)(A + (size_t)n * K + (kq << 2));
    ldsT[((kq << 2) + 0) * NBp + r] = v.x;
    ldsT[((kq << 2) + 1) * NBp + r] = v.y;
    ldsT[((kq << 2) + 2) * NBp + r] = v.z;
    ldsT[((kq << 2) + 3) * NBp + r] = v.w;
  }
  __syncthreads();
  const int o0 = __builtin_amdgcn_readfirstlane(tid / NB) * MO;
  const int nl = tid & (NB - 1);
  const int n = nb0 + nl;
  float acc[MO];
#pragma unroll
  for (int m = 0; m < MO; ++m) acc[m] = 0.f;
#pragma unroll 4
  for (int k = 0; k < K; ++k) {
    float a = ldsT[k * NBp + nl];
    const float* wr = Wk + k * OUTT + o0;   // wave-uniform -> s_load
#pragma unroll
    for (int m = 0; m < MO; ++m) acc[m] += a * wr[m];
  }
  if (n < NNODES) {
    float sc = 1.f;
    if (DEGBIAS) sc = 1.f / (float)(rowptr[n + 1] - rowptr[n] + 1);
#pragma unroll
    for (int m4 = 0; m4 < MO / 4; ++m4) {
      float4 v;
      if (DEGBIAS) {
        v.x = fmaxf(acc[m4 * 4 + 0] * sc + bptr[o0 + m4 * 4 + 0], 0.f);
        v.y = fmaxf(acc[m4 * 4 + 1] * sc + bptr[o0 + m4 * 4 + 1], 0.f);
        v.z = fmaxf(acc[m4 * 4 + 2] * sc + bptr[o0 + m4 * 4 + 2], 0.f);
        v.w = fmaxf(acc[m4 * 4 + 3] * sc + bptr[o0 + m4 * 4 + 3], 0.f);
      } else {
        v = make_float4(acc[m4 * 4 + 0], acc[m4 * 4 + 1],
                        acc[m4 * 4 + 2], acc[m4 * 4 + 3]);
      }
      *(float4*)(C + (size_t)n * OUTT + o0 + m4 * 4) = v;
    }
  }
}

// ---------------- s = x @ u  ([N,4]) ----------------
template<int FIN>
__global__ __launch_bounds__(256) void s_kernel(const float* __restrict__ x,
                                                const float* __restrict__ u,
                                                float* __restrict__ s) {
  int tid = blockIdx.x * 256 + threadIdx.x;
  int n = tid >> 2, h = tid & 3;
  if (n >= NNODES) return;
  const float4* xr = (const float4*)(x + (size_t)n * FIN);
  float acc = 0.f;
#pragma unroll
  for (int f4 = 0; f4 < FIN / 4; ++f4) {
    float4 xv = xr[f4];
    acc += xv.x * u[(4 * f4 + 0) * 4 + h] + xv.y * u[(4 * f4 + 1) * 4 + h] +
           xv.z * u[(4 * f4 + 2) * 4 + h] + xv.w * u[(4 * f4 + 3) * 4 + h];
  }
  s[tid] = acc;  // tid == n*4+h
}

// ---------------- layer-1 gather over t, fused softmax ----------------
// 8 lanes/node, each lane owns outputs o=2*lane,2*lane+1 (two float4 t-slices).
__global__ __launch_bounds__(256) void gather1_kernel(const int* __restrict__ rowptr,
                                                      const int* __restrict__ col,
                                                      const float* __restrict__ s,
                                                      const float* __restrict__ t,
                                                      const float* __restrict__ cptr,
                                                      const float* __restrict__ bptr,
                                                      float* __restrict__ h) {
  const int lane = threadIdx.x & 7;
  const int sub = threadIdx.x >> 3;
  const int n = blockIdx.x * 32 + sub;
  if (n >= NNODES) return;
  float4 c4 = *(const float4*)cptr;
  float mxc = fmaxf(fmaxf(c4.x, c4.y), fmaxf(c4.z, c4.w));
  float4 qs = make_float4(__expf(c4.x - mxc), __expf(c4.y - mxc),
                          __expf(c4.z - mxc), __expf(c4.w - mxc));
  float sinv = 1.f / (qs.x + qs.y + qs.z + qs.w);
  qs.x *= sinv; qs.y *= sinv; qs.z *= sinv; qs.w *= sinv;
  float4 sd = *(const float4*)(s + 4 * (size_t)n);
  const float4* trow = (const float4*)(t + (size_t)n * 64);
  float acc0 = dot4(qs, trow[2 * lane + 0]);
  float acc1 = dot4(qs, trow[2 * lane + 1]);
  const int beg = rowptr[n], end = rowptr[n + 1];
  int idx = beg;
  for (; idx + 3 < end; idx += 4) {
    int s0 = col[idx], s1 = col[idx + 1], s2 = col[idx + 2], s3 = col[idx + 3];
    float4 a0 = *(const float4*)(s + 4 * (size_t)s0);
    float4 a1 = *(const float4*)(s + 4 * (size_t)s1);
    float4 a2 = *(const float4*)(s + 4 * (size_t)s2);
    float4 a3 = *(const float4*)(s + 4 * (size_t)s3);
    const float4* t0 = (const float4*)(t + (size_t)s0 * 64) + 2 * lane;
    const float4* t1 = (const float4*)(t + (size_t)s1 * 64) + 2 * lane;
    const float4* t2 = (const float4*)(t + (size_t)s2 * 64) + 2 * lane;
    const float4* t3 = (const float4*)(t + (size_t)s3 * 64) + 2 * lane;
    float4 u0 = t0[0], v0 = t0[1];
    float4 u1 = t1[0], v1 = t1[1];
    float4 u2 = t2[0], v2 = t2[1];
    float4 u3 = t3[0], v3 = t3[1];
    float4 q0 = softq(a0, sd, c4);
    float4 q1 = softq(a1, sd, c4);
    float4 q2 = softq(a2, sd, c4);
    float4 q3 = softq(a3, sd, c4);
    acc0 += dot4(q0, u0) + dot4(q1, u1) + dot4(q2, u2) + dot4(q3, u3);
    acc1 += dot4(q0, v0) + dot4(q1, v1) + dot4(q2, v2) + dot4(q3, v3);
  }
  for (; idx < end; ++idx) {
    int src = col[idx];
    float4 qv = softq(*(const float4*)(s + 4 * (size_t)src), sd, c4);
    const float4* tw = (const float4*)(t + (size_t)src * 64) + 2 * lane;
    acc0 += dot4(qv, tw[0]);
    acc1 += dot4(qv, tw[1]);
  }
  float d = 1.f / (float)(end - beg + 1);
  h[(size_t)n * 16 + 2 * lane + 0] = fmaxf(acc0 * d + bptr[2 * lane + 0], 0.f);
  h[(size_t)n * 16 + 2 * lane + 1] = fmaxf(acc1 * d + bptr[2 * lane + 1], 0.f);
}

// ---------------- g-gather, fused softmax, float4-per-lane features ----------
// LPN = FIN/4 lanes per node (4 or 8); lane owns features [4*lane..4*lane+3].
template<int FIN>
__global__ __launch_bounds__(256) void gatherG_kernel(const int* __restrict__ rowptr,
                                                      const int* __restrict__ col,
                                                      const float* __restrict__ s,
                                                      const float* __restrict__ x,
                                                      const float* __restrict__ cptr,
                                                      float* __restrict__ g) {
  constexpr int LPN = FIN / 4;
  constexpr int NSUB = 256 / LPN;
  const int lane = threadIdx.x & (LPN - 1);
  const int sub = threadIdx.x / LPN;
  const int n = blockIdx.x * NSUB + sub;
  if (n >= NNODES) return;
  float4 c4 = *(const float4*)cptr;
  float mxc = fmaxf(fmaxf(c4.x, c4.y), fmaxf(c4.z, c4.w));
  float4 qsl = make_float4(__expf(c4.x - mxc), __expf(c4.y - mxc),
                           __expf(c4.z - mxc), __expf(c4.w - mxc));
  float sinv = 1.f / (qsl.x + qsl.y + qsl.z + qsl.w);
  qsl.x *= sinv; qsl.y *= sinv; qsl.z *= sinv; qsl.w *= sinv;
  float4 sd = *(const float4*)(s + 4 * (size_t)n);
  float4 xn = *((const float4*)(x + (size_t)n * FIN) + lane);
  float4 g0 = make_float4(qsl.x * xn.x, qsl.x * xn.y, qsl.x * xn.z, qsl.x * xn.w);
  float4 g1 = make_float4(qsl.y * xn.x, qsl.y * xn.y, qsl.y * xn.z, qsl.y * xn.w);
  float4 g2 = make_float4(qsl.z * xn.x, qsl.z * xn.y, qsl.z * xn.z, qsl.z * xn.w);
  float4 g3 = make_float4(qsl.w * xn.x, qsl.w * xn.y, qsl.w * xn.z, qsl.w * xn.w);
  const int beg = rowptr[n], end = rowptr[n + 1];
  int idx = beg;
  for (; idx + 3 < end; idx += 4) {
    int s0 = col[idx], s1 = col[idx + 1], s2 = col[idx + 2], s3 = col[idx + 3];
    float4 a0 = *(const float4*)(s + 4 * (size_t)s0);
    float4 a1 = *(const float4*)(s + 4 * (size_t)s1);
    float4 a2 = *(const float4*)(s + 4 * (size_t)s2);
    float4 a3 = *(const float4*)(s + 4 * (size_t)s3);
    float4 x0 = *((const float4*)(x + (size_t)s0 * FIN) + lane);
    float4 x1 = *((const float4*)(x + (size_t)s1 * FIN) + lane);
    float4 x2 = *((const float4*)(x + (size_t)s2 * FIN) + lane);
    float4 x3 = *((const float4*)(x + (size_t)s3 * FIN) + lane);
    float4 q0 = softq(a0, sd, c4);
    float4 q1 = softq(a1, sd, c4);
    float4 q2 = softq(a2, sd, c4);
    float4 q3 = softq(a3, sd, c4);
    fma4(g0, q0.x, x0); fma4(g1, q0.y, x0); fma4(g2, q0.z, x0); fma4(g3, q0.w, x0);
    fma4(g0, q1.x, x1); fma4(g1, q1.y, x1); fma4(g2, q1.z, x1); fma4(g3, q1.w, x1);
    fma4(g0, q2.x, x2); fma4(g1, q2.y, x2); fma4(g2, q2.z, x2); fma4(g3, q2.w, x2);
    fma4(g0, q3.x, x3); fma4(g1, q3.y, x3); fma4(g2, q3.z, x3); fma4(g3, q3.w, x3);
  }
  for (; idx < end; ++idx) {
    int src = col[idx];
    float4 qv = softq(*(const float4*)(s + 4 * (size_t)src), sd, c4);
    float4 xv = *((const float4*)(x + (size_t)src * FIN) + lane);
    fma4(g0, qv.x, xv); fma4(g1, qv.y, xv); fma4(g2, qv.z, xv); fma4(g3, qv.w, xv);
  }
  float* gr = g + (size_t)n * 4 * FIN;
  *(float4*)(gr + 0 * FIN + 4 * lane) = g0;
  *(float4*)(gr + 1 * FIN + 4 * lane) = g1;
  *(float4*)(gr + 2 * FIN + 4 * lane) = g2;
  *(float4*)(gr + 3 * FIN + 4 * lane) = g3;
}

// ---------------- BN batch-stats over h3 [N,64] ----------------
__global__ __launch_bounds__(256) void stats_kernel(const float* __restrict__ h3,
                                                    float* __restrict__ sums) {
  const int o = threadIdx.x & 63;
  const int r = threadIdx.x >> 6;
  float accS = 0.f, accQ = 0.f;
  for (int base = blockIdx.x * 4; base < NNODES; base += gridDim.x * 4) {
    int n = base + r;
    if (n < NNODES) {
      float v = h3[(size_t)n * 64 + o];
      accS += v;
      accQ += v * v;
    }
  }
  __shared__ float ls[256], lq[256];
  ls[threadIdx.x] = accS;
  lq[threadIdx.x] = accQ;
  __syncthreads();
  if (threadIdx.x < 64) {
    float a = ls[threadIdx.x] + ls[threadIdx.x + 64] + ls[threadIdx.x + 128] + ls[threadIdx.x + 192];
    float qq = lq[threadIdx.x] + lq[threadIdx.x + 64] + lq[threadIdx.x + 128] + lq[threadIdx.x + 192];
    atomicAdd(&sums[threadIdx.x], a);
    atomicAdd(&sums[64 + threadIdx.x], qq);
  }
}

// ---------------- BN + MLP head + sigmoid, one thread per node ----------------
__global__ __launch_bounds__(256) void mlp_kernel(
    const float* __restrict__ h3, const float* __restrict__ sums,
    const float* __restrict__ gamma, const float* __restrict__ beta,
    const float* __restrict__ lw1, const float* __restrict__ lb1,
    const float* __restrict__ lw2, const float* __restrict__ lb2,
    const float* __restrict__ lw3, const float* __restrict__ lb3,
    const float* __restrict__ lw4, const float* __restrict__ lb4,
    const float* __restrict__ ow, const float* __restrict__ ob,
    float* __restrict__ out) {
  __shared__ float w1[64 * 32], w2[32 * 16], w3[16 * 8], w4[8 * 4];
  __shared__ float b1s[32], b2s[16], b3s[8], b4s[4], wos[4];
  __shared__ float scale[64], shift[64];
  int tid = threadIdx.x;
  for (int i = tid; i < 64 * 32; i += 256) w1[i] = lw1[i];
  for (int i = tid; i < 32 * 16; i += 256) w2[i] = lw2[i];
  if (tid < 128) w3[tid] = lw3[tid];
  if (tid < 32) { w4[tid] = lw4[tid]; b1s[tid] = lb1[tid]; }
  if (tid < 16) b2s[tid] = lb2[tid];
  if (tid < 8) b3s[tid] = lb3[tid];
  if (tid < 4) { b4s[tid] = lb4[tid]; wos[tid] = ow[tid]; }
  if (tid < 64) {
    float mu = sums[tid] * (1.f / NNODES);
    float var = sums[64 + tid] * (1.f / NNODES) - mu * mu;
    float sc = rsqrtf(var + 1e-5f) * gamma[tid];
    scale[tid] = sc;
    shift[tid] = beta[tid] - mu * sc;
  }
  __syncthreads();
  int n = blockIdx.x * 256 + tid;
  if (n >= NNODES) return;
  float obv = ob[0];
  const float4* hr = (const float4*)(h3 + (size_t)n * 64);
  float z1[32];
#pragma unroll
  for (int j = 0; j < 32; ++j) z1[j] = b1s[j];
  for (int i4 = 0; i4 < 16; ++i4) {
    float4 hv = hr[i4];
    float a0 = hv.x * scale[4 * i4 + 0] + shift[4 * i4 + 0];
    float a1 = hv.y * scale[4 * i4 + 1] + shift[4 * i4 + 1];
    float a2 = hv.z * scale[4 * i4 + 2] + shift[4 * i4 + 2];
    float a3 = hv.w * scale[4 * i4 + 3] + shift[4 * i4 + 3];
#pragma unroll
    for (int j = 0; j < 32; ++j) {
      z1[j] += a0 * w1[(4 * i4 + 0) * 32 + j] + a1 * w1[(4 * i4 + 1) * 32 + j] +
               a2 * w1[(4 * i4 + 2) * 32 + j] + a3 * w1[(4 * i4 + 3) * 32 + j];
    }
  }
  float z2[16];
#pragma unroll
  for (int j = 0; j < 16; ++j) z2[j] = b2s[j];
  for (int i = 0; i < 32; ++i) {
    float a = fmaxf(z1[i], 0.f);
#pragma unroll
    for (int j = 0; j < 16; ++j) z2[j] += a * w2[i * 16 + j];
  }
  float z3[8];
#pragma unroll
  for (int j = 0; j < 8; ++j) z3[j] = b3s[j];
  for (int i = 0; i < 16; ++i) {
    float a = fmaxf(z2[i], 0.f);
#pragma unroll
    for (int j = 0; j < 8; ++j) z3[j] += a * w3[i * 8 + j];
  }
  float z4[4];
#pragma unroll
  for (int j = 0; j < 4; ++j) z4[j] = b4s[j];
  for (int i = 0; i < 8; ++i) {
    float a = fmaxf(z3[i], 0.f);
#pragma unroll
    for (int j = 0; j < 4; ++j) z4[j] += a * w4[i * 4 + j];
  }
  float zo = obv;
#pragma unroll
  for (int i = 0; i < 4; ++i) zo += fmaxf(z4[i], 0.f) * wos[i];
  out[n] = 1.f / (1.f + __expf(-zo));
}

extern "C" void kernel_launch(void* const* d_in, const int* in_sizes, int n_in,
                              void* d_out, int out_size, void* d_ws, size_t ws_size,
                              hipStream_t stream) {
  const float* x  = (const float*)d_in[0];
  const int*   ei = (const int*)d_in[1];
  const float* W1 = (const float*)d_in[2];  const float* u1 = (const float*)d_in[3];
  const float* c1 = (const float*)d_in[4];  const float* b1 = (const float*)d_in[5];
  const float* W2 = (const float*)d_in[6];  const float* u2 = (const float*)d_in[7];
  const float* c2 = (const float*)d_in[8];  const float* b2 = (const float*)d_in[9];
  const float* W3 = (const float*)d_in[10]; const float* u3 = (const float*)d_in[11];
  const float* c3 = (const float*)d_in[12]; const float* b3 = (const float*)d_in[13];
  const float* gamma = (const float*)d_in[14]; const float* beta = (const float*)d_in[15];
  const float* lw1 = (const float*)d_in[16]; const float* lb1 = (const float*)d_in[17];
  const float* lw2 = (const float*)d_in[18]; const float* lb2 = (const float*)d_in[19];
  const float* lw3 = (const float*)d_in[20]; const float* lb3 = (const float*)d_in[21];
  const float* lw4 = (const float*)d_in[22]; const float* lb4 = (const float*)d_in[23];
  const float* ow  = (const float*)d_in[24]; const float* ob  = (const float*)d_in[25];
  float* out = (float*)d_out;

  float* t    = (float*)d_ws;                         // N*64   (layer-1 t)
  float* g    = t + (size_t)NNODES * 64;              // N*128  (g buffer, max 4*32)
  float* hA   = g + (size_t)NNODES * 128;             // N*64
  float* hB   = hA + (size_t)NNODES * 64;             // N*64
  float* s    = hB + (size_t)NNODES * 64;             // N*4
  float* sums = s + (size_t)NNODES * 4;               // 128
  float* Wk1  = sums + 128;                           // 4096
  float* Wk2  = Wk1 + 4096;                           // 2048
  float* Wk3  = Wk2 + 2048;                           // 8192
  int*   rowptr   = (int*)(Wk3 + 8192);               // N+1 (pad 8)
  int*   counts   = rowptr + NNODES + 8;              // N
  int*   blockSum = counts + NNODES;                  // 256
  int*   blockOff = blockSum + 256;                   // 256
  int*   col      = blockOff + 256;                   // E
  int*   rank     = col + NEDGES;                     // E

  hipMemsetAsync(counts, 0, NNODES * sizeof(int), stream);
  hipMemsetAsync(sums, 0, 128 * sizeof(float), stream);

  // ---- W transposes + CSR by dst ----
  prep_kernel<<<56, 256, 0, stream>>>(W1, W2, W3, Wk1, Wk2, Wk3);
  hist_kernel<<<(NEDGES + 255) / 256, 256, 0, stream>>>(ei, counts, rank);
  scanA_kernel<<<SCAN_BLOCKS, 256, 0, stream>>>(counts, rowptr, blockSum);
  scanB_kernel<<<1, 256, 0, stream>>>(blockSum, blockOff);
  scanC_kernel<<<SCAN_BLOCKS, 256, 0, stream>>>(rowptr, blockOff);
  scatter_kernel<<<NSLICE * 8, 256, 0, stream>>>(ei, rowptr, rank, col);

  // ---- layer 1: 64 -> 16 (t-gather, fused softmax) ----
  ngemm_kernel<64, 64, 16, false><<<(NNODES + 63) / 64, 256, 0, stream>>>(x, Wk1, nullptr, nullptr, t);
  s_kernel<64><<<(NNODES * 4 + 255) / 256, 256, 0, stream>>>(x, u1, s);
  gather1_kernel<<<(NNODES + 31) / 32, 256, 0, stream>>>(rowptr, col, s, t, c1, b1, hA);

  // ---- layer 2: 16 -> 32 (g-gather, fused softmax) ----
  s_kernel<16><<<(NNODES * 4 + 255) / 256, 256, 0, stream>>>(hA, u2, s);
  gatherG_kernel<16><<<(NNODES + 63) / 64, 256, 0, stream>>>(rowptr, col, s, hA, c2, g);
  ngemm_kernel<64, 32, 16, true><<<(NNODES + 127) / 128, 256, 0, stream>>>(g, Wk2, rowptr, b2, hB);

  // ---- layer 3: 32 -> 64 (g-gather, fused softmax) ----
  s_kernel<32><<<(NNODES * 4 + 255) / 256, 256, 0, stream>>>(hB, u3, s);
  gatherG_kernel<32><<<(NNODES + 31) / 32, 256, 0, stream>>>(rowptr, col, s, hB, c3, g);
  ngemm_kernel<128, 64, 16, true><<<(NNODES + 63) / 64, 256, 0, stream>>>(g, Wk3, rowptr, b3, hA);

  // ---- BN stats + MLP head ----
  stats_kernel<<<256, 256, 0, stream>>>(hA, sums);
  mlp_kernel<<<(NNODES + 255) / 256, 256, 0, stream>>>(hA, sums, gamma, beta, lw1, lb1,
                                                       lw2, lb2, lw3, lb3, lw4, lb4,
                                                       ow, ob, out);
}

// Round 14
// 245.358 us; speedup vs baseline: 1.1823x; 1.0853x over previous
//
#include <hip/hip_runtime.h>

#define NNODES 50000
#define NEDGES 800000
#define SCAN_BLOCKS ((NNODES + 255) / 256)   // 196
#define NPART (NNODES / 8)                   // 6250 nodes per XCD partition
#define EPS 2048                             // edges per slice
#define NSLICE ((NEDGES + EPS - 1) / EPS)    // 391

// per-edge attention weights: softmax over heads of (s_src - s_dst + c)
__device__ __forceinline__ float4 softq(float4 ss, float4 sd, float4 c4) {
  float l0 = ss.x - sd.x + c4.x;
  float l1 = ss.y - sd.y + c4.y;
  float l2 = ss.z - sd.z + c4.z;
  float l3 = ss.w - sd.w + c4.w;
  float mx = fmaxf(fmaxf(l0, l1), fmaxf(l2, l3));
  float e0 = __expf(l0 - mx), e1 = __expf(l1 - mx);
  float e2 = __expf(l2 - mx), e3 = __expf(l3 - mx);
  float inv = 1.f / (e0 + e1 + e2 + e3);
  return make_float4(e0 * inv, e1 * inv, e2 * inv, e3 * inv);
}

__device__ __forceinline__ void fma4(float4& a, float q, float4 v) {
  a.x += q * v.x; a.y += q * v.y; a.z += q * v.z; a.w += q * v.w;
}
__device__ __forceinline__ float dot4(float4 a, float4 b) {
  return a.x * b.x + a.y * b.y + a.z * b.z + a.w * b.w;
}
// store float4 to 4 consecutive-k slots of ldsT[k][nl]
__device__ __forceinline__ void st4T(float* ldsT, int k0, int NBp, int nl, float4 v) {
  ldsT[(k0 + 0) * NBp + nl] = v.x;
  ldsT[(k0 + 1) * NBp + nl] = v.y;
  ldsT[(k0 + 2) * NBp + nl] = v.z;
  ldsT[(k0 + 3) * NBp + nl] = v.w;
}

// ---------------- CSR build: histogram over dst + per-edge rank ----------------
__global__ __launch_bounds__(256) void hist_kernel(const int* __restrict__ ei,
                                                   int* __restrict__ counts,
                                                   int* __restrict__ rank) {
  int e = blockIdx.x * 256 + threadIdx.x;
  if (e < NEDGES) rank[e] = atomicAdd(&counts[ei[NEDGES + e]], 1);
}

__global__ __launch_bounds__(256) void scanA_kernel(const int* __restrict__ counts,
                                                    int* __restrict__ rowptr,
                                                    int* __restrict__ blockSum) {
  __shared__ int sm[256];
  int i = blockIdx.x * 256 + threadIdx.x;
  int v = (i < NNODES) ? counts[i] : 0;
  sm[threadIdx.x] = v;
  __syncthreads();
  for (int off = 1; off < 256; off <<= 1) {
    int x = (threadIdx.x >= off) ? sm[threadIdx.x - off] : 0;
    __syncthreads();
    sm[threadIdx.x] += x;
    __syncthreads();
  }
  if (i < NNODES) rowptr[i] = sm[threadIdx.x] - v;
  if (threadIdx.x == 255) blockSum[blockIdx.x] = sm[255];
}

__global__ __launch_bounds__(256) void scanB_kernel(int* __restrict__ blockSum,
                                                    int* __restrict__ blockOff) {
  __shared__ int sm[256];
  int v = (threadIdx.x < SCAN_BLOCKS) ? blockSum[threadIdx.x] : 0;
  sm[threadIdx.x] = v;
  __syncthreads();
  for (int off = 1; off < 256; off <<= 1) {
    int x = (threadIdx.x >= off) ? sm[threadIdx.x - off] : 0;
    __syncthreads();
    sm[threadIdx.x] += x;
    __syncthreads();
  }
  if (threadIdx.x < SCAN_BLOCKS) blockOff[threadIdx.x] = sm[threadIdx.x] - v;
}

__global__ __launch_bounds__(256) void scanC_kernel(int* __restrict__ rowptr,
                                                    const int* __restrict__ blockOff) {
  int i = blockIdx.x * 256 + threadIdx.x;
  if (i < NNODES) rowptr[i] += blockOff[blockIdx.x];
  if (i == 0) rowptr[NNODES] = NEDGES;
}

// Atomic-free XCD-partitioned scatter.
__global__ __launch_bounds__(256) void scatter_kernel(const int* __restrict__ ei,
                                                      const int* __restrict__ rowptr,
                                                      const int* __restrict__ rank,
                                                      int* __restrict__ col) {
  const int p = blockIdx.x & 7;
  const int sl = blockIdx.x >> 3;
  const int P0 = p * NPART;
  const int e1 = min((sl + 1) * EPS, NEDGES);
  for (int e = sl * EPS + threadIdx.x; e < e1; e += 256) {
    int dst = __builtin_nontemporal_load(&ei[NEDGES + e]);
    if ((unsigned)(dst - P0) < (unsigned)NPART) {
      int pos = rowptr[dst] + __builtin_nontemporal_load(&rank[e]);
      col[pos] = __builtin_nontemporal_load(&ei[e]);
    }
  }
}

// ---------------- W pre-transpose into [k][o] rows (scalar-load friendly) ----
__global__ __launch_bounds__(256) void prep_kernel(const float* __restrict__ W1,
                                                   const float* __restrict__ W2,
                                                   const float* __restrict__ W3,
                                                   float* __restrict__ Wk1,
                                                   float* __restrict__ Wk2,
                                                   float* __restrict__ Wk3) {
  int i = blockIdx.x * 256 + threadIdx.x;
  if (i < 4096) {
    int f = i >> 6, j = i & 63;
    Wk1[i] = W1[f * 64 + ((j & 3) << 4) + (j >> 2)];
  } else if (i < 6144) {
    int i2 = i - 4096;
    int k = i2 >> 5, o = i2 & 31;
    int hh = k >> 4, f = k & 15;
    Wk2[i2] = W2[f * 128 + hh * 32 + o];
  } else if (i < 14336) {
    int i3 = i - 6144;
    int k = i3 >> 6, o = i3 & 63;
    int hh = k >> 5, f = k & 31;
    Wk3[i3] = W3[f * 256 + hh * 64 + o];
  }
}

// ---------------- layer-1 t GEMM: t[n][j] = x[n][:64] . Wk1[j][:64] ----------
template<int K, int OUTT, int MO, bool DEGBIAS>
__global__ __launch_bounds__(256) void ngemm_kernel(const float* __restrict__ A,
                                                    const float* __restrict__ Wk,
                                                    const int* __restrict__ rowptr,
                                                    const float* __restrict__ bptr,
                                                    float* __restrict__ C) {
  constexpr int OG = OUTT / MO;
  constexpr int NB = 256 / OG;
  constexpr int NBp = NB + 1;
  __shared__ float ldsT[K * NBp];
  const int tid = threadIdx.x;
  const int nb0 = blockIdx.x * NB;
  for (int i = tid; i < NB * (K / 4); i += 256) {
    int r = i / (K / 4), kq = i - r * (K / 4);
    int n = nb0 + r;
    if (n >= NNODES) n = NNODES - 1;
    float4 v = *(const float4*)(A + (size_t)n * K + (kq << 2));
    st4T(ldsT, kq << 2, NBp, r, v);
  }
  __syncthreads();
  const int o0 = __builtin_amdgcn_readfirstlane(tid / NB) * MO;
  const int nl = tid & (NB - 1);
  const int n = nb0 + nl;
  float acc[MO];
#pragma unroll
  for (int m = 0; m < MO; ++m) acc[m] = 0.f;
#pragma unroll 4
  for (int k = 0; k < K; ++k) {
    float a = ldsT[k * NBp + nl];
    const float* wr = Wk + k * OUTT + o0;   // wave-uniform -> s_load
#pragma unroll
    for (int m = 0; m < MO; ++m) acc[m] += a * wr[m];
  }
  if (n < NNODES) {
    float sc = 1.f;
    if (DEGBIAS) sc = 1.f / (float)(rowptr[n + 1] - rowptr[n] + 1);
#pragma unroll
    for (int m4 = 0; m4 < MO / 4; ++m4) {
      float4 v;
      if (DEGBIAS) {
        v.x = fmaxf(acc[m4 * 4 + 0] * sc + bptr[o0 + m4 * 4 + 0], 0.f);
        v.y = fmaxf(acc[m4 * 4 + 1] * sc + bptr[o0 + m4 * 4 + 1], 0.f);
        v.z = fmaxf(acc[m4 * 4 + 2] * sc + bptr[o0 + m4 * 4 + 2], 0.f);
        v.w = fmaxf(acc[m4 * 4 + 3] * sc + bptr[o0 + m4 * 4 + 3], 0.f);
      } else {
        v = make_float4(acc[m4 * 4 + 0], acc[m4 * 4 + 1],
                        acc[m4 * 4 + 2], acc[m4 * 4 + 3]);
      }
      *(float4*)(C + (size_t)n * OUTT + o0 + m4 * 4) = v;
    }
  }
}

// ---------------- fused g-gather + transform (layers 2/3) ----------------
// Phase 1: gather with fused softmax, 8 features/lane (LPN=FIN/8 lanes/node),
// accumulators written straight into the transposed LDS tile ldsT[k][n].
// Phase 2: round-11 ngemm loop (1 ds_read + MO FMA per k, W via s_load),
// /deg + bias + relu epilogue, h written directly. No global g round-trip.
template<int FIN, int OUTT, int MO>
__global__ __launch_bounds__(256) void fusedG_kernel(const int* __restrict__ rowptr,
                                                     const int* __restrict__ col,
                                                     const float* __restrict__ s,
                                                     const float* __restrict__ x,
                                                     const float* __restrict__ Wk,
                                                     const float* __restrict__ cptr,
                                                     const float* __restrict__ bptr,
                                                     float* __restrict__ h) {
  constexpr int LPN = FIN / 8;        // lanes per node (2 or 4)
  constexpr int NB = 256 / LPN;       // nodes per block (128 or 64)
  constexpr int NBp = NB + 1;
  constexpr int K = 4 * FIN;
  constexpr int OG = OUTT / MO;       // must equal 256/NB (wave-uniform o0)
  static_assert(OG == 256 / NB, "geometry mismatch");
  __shared__ float ldsT[K * NBp];
  const int tid = threadIdx.x;
  const int nb0 = blockIdx.x * NB;

  // ---- phase 1: gather ----
  {
    const int lane = tid & (LPN - 1);
    const int sub = tid / LPN;
    int n = nb0 + sub;
    if (n >= NNODES) n = NNODES - 1;   // duplicate work, discarded in phase 2
    float4 c4 = *(const float4*)cptr;
    float mxc = fmaxf(fmaxf(c4.x, c4.y), fmaxf(c4.z, c4.w));
    float4 qsl = make_float4(__expf(c4.x - mxc), __expf(c4.y - mxc),
                             __expf(c4.z - mxc), __expf(c4.w - mxc));
    float sinv = 1.f / (qsl.x + qsl.y + qsl.z + qsl.w);
    qsl.x *= sinv; qsl.y *= sinv; qsl.z *= sinv; qsl.w *= sinv;
    float4 sd = *(const float4*)(s + 4 * (size_t)n);
    const float4* xn = (const float4*)(x + (size_t)n * FIN) + 2 * lane;
    float4 xa = xn[0], xb = xn[1];
    float4 g0a = make_float4(qsl.x * xa.x, qsl.x * xa.y, qsl.x * xa.z, qsl.x * xa.w);
    float4 g0b = make_float4(qsl.x * xb.x, qsl.x * xb.y, qsl.x * xb.z, qsl.x * xb.w);
    float4 g1a = make_float4(qsl.y * xa.x, qsl.y * xa.y, qsl.y * xa.z, qsl.y * xa.w);
    float4 g1b = make_float4(qsl.y * xb.x, qsl.y * xb.y, qsl.y * xb.z, qsl.y * xb.w);
    float4 g2a = make_float4(qsl.z * xa.x, qsl.z * xa.y, qsl.z * xa.z, qsl.z * xa.w);
    float4 g2b = make_float4(qsl.z * xb.x, qsl.z * xb.y, qsl.z * xb.z, qsl.z * xb.w);
    float4 g3a = make_float4(qsl.w * xa.x, qsl.w * xa.y, qsl.w * xa.z, qsl.w * xa.w);
    float4 g3b = make_float4(qsl.w * xb.x, qsl.w * xb.y, qsl.w * xb.z, qsl.w * xb.w);
    const int beg = rowptr[n], end = rowptr[n + 1];
    int idx = beg;
    for (; idx + 1 < end; idx += 2) {
      int s0 = col[idx], s1 = col[idx + 1];
      float4 a0 = *(const float4*)(s + 4 * (size_t)s0);
      float4 a1 = *(const float4*)(s + 4 * (size_t)s1);
      const float4* xr0 = (const float4*)(x + (size_t)s0 * FIN) + 2 * lane;
      const float4* xr1 = (const float4*)(x + (size_t)s1 * FIN) + 2 * lane;
      float4 x0a = xr0[0], x0b = xr0[1];
      float4 x1a = xr1[0], x1b = xr1[1];
      float4 q0 = softq(a0, sd, c4);
      float4 q1 = softq(a1, sd, c4);
      fma4(g0a, q0.x, x0a); fma4(g0b, q0.x, x0b);
      fma4(g1a, q0.y, x0a); fma4(g1b, q0.y, x0b);
      fma4(g2a, q0.z, x0a); fma4(g2b, q0.z, x0b);
      fma4(g3a, q0.w, x0a); fma4(g3b, q0.w, x0b);
      fma4(g0a, q1.x, x1a); fma4(g0b, q1.x, x1b);
      fma4(g1a, q1.y, x1a); fma4(g1b, q1.y, x1b);
      fma4(g2a, q1.z, x1a); fma4(g2b, q1.z, x1b);
      fma4(g3a, q1.w, x1a); fma4(g3b, q1.w, x1b);
    }
    if (idx < end) {
      int s0 = col[idx];
      float4 qv = softq(*(const float4*)(s + 4 * (size_t)s0), sd, c4);
      const float4* xr0 = (const float4*)(x + (size_t)s0 * FIN) + 2 * lane;
      float4 x0a = xr0[0], x0b = xr0[1];
      fma4(g0a, qv.x, x0a); fma4(g0b, qv.x, x0b);
      fma4(g1a, qv.y, x0a); fma4(g1b, qv.y, x0b);
      fma4(g2a, qv.z, x0a); fma4(g2b, qv.z, x0b);
      fma4(g3a, qv.w, x0a); fma4(g3b, qv.w, x0b);
    }
    // write to transposed tile: k = hh*FIN + 8*lane + j
    const int f0 = 8 * lane;
    st4T(ldsT, 0 * FIN + f0, NBp, sub, g0a); st4T(ldsT, 0 * FIN + f0 + 4, NBp, sub, g0b);
    st4T(ldsT, 1 * FIN + f0, NBp, sub, g1a); st4T(ldsT, 1 * FIN + f0 + 4, NBp, sub, g1b);
    st4T(ldsT, 2 * FIN + f0, NBp, sub, g2a); st4T(ldsT, 2 * FIN + f0 + 4, NBp, sub, g2b);
    st4T(ldsT, 3 * FIN + f0, NBp, sub, g3a); st4T(ldsT, 3 * FIN + f0 + 4, NBp, sub, g3b);
  }
  __syncthreads();

  // ---- phase 2: transform ----
  const int o0 = __builtin_amdgcn_readfirstlane(tid / NB) * MO;
  const int nl = tid & (NB - 1);
  const int n = nb0 + nl;
  float acc[MO];
#pragma unroll
  for (int m = 0; m < MO; ++m) acc[m] = 0.f;
#pragma unroll 4
  for (int k = 0; k < K; ++k) {
    float a = ldsT[k * NBp + nl];
    const float* wr = Wk + k * OUTT + o0;   // wave-uniform -> s_load
#pragma unroll
    for (int m = 0; m < MO; ++m) acc[m] += a * wr[m];
  }
  if (n < NNODES) {
    float sc = 1.f / (float)(rowptr[n + 1] - rowptr[n] + 1);
#pragma unroll
    for (int m4 = 0; m4 < MO / 4; ++m4) {
      float4 v;
      v.x = fmaxf(acc[m4 * 4 + 0] * sc + bptr[o0 + m4 * 4 + 0], 0.f);
      v.y = fmaxf(acc[m4 * 4 + 1] * sc + bptr[o0 + m4 * 4 + 1], 0.f);
      v.z = fmaxf(acc[m4 * 4 + 2] * sc + bptr[o0 + m4 * 4 + 2], 0.f);
      v.w = fmaxf(acc[m4 * 4 + 3] * sc + bptr[o0 + m4 * 4 + 3], 0.f);
      *(float4*)(h + (size_t)n * OUTT + o0 + m4 * 4) = v;
    }
  }
}

// ---------------- s = x @ u  ([N,4]) ----------------
template<int FIN>
__global__ __launch_bounds__(256) void s_kernel(const float* __restrict__ x,
                                                const float* __restrict__ u,
                                                float* __restrict__ s) {
  int tid = blockIdx.x * 256 + threadIdx.x;
  int n = tid >> 2, h = tid & 3;
  if (n >= NNODES) return;
  const float4* xr = (const float4*)(x + (size_t)n * FIN);
  float acc = 0.f;
#pragma unroll
  for (int f4 = 0; f4 < FIN / 4; ++f4) {
    float4 xv = xr[f4];
    acc += xv.x * u[(4 * f4 + 0) * 4 + h] + xv.y * u[(4 * f4 + 1) * 4 + h] +
           xv.z * u[(4 * f4 + 2) * 4 + h] + xv.w * u[(4 * f4 + 3) * 4 + h];
  }
  s[tid] = acc;  // tid == n*4+h
}

// ---------------- layer-1 gather over t, fused softmax ----------------
// 8 lanes/node, each lane owns outputs o=2*lane,2*lane+1 (two float4 t-slices).
__global__ __launch_bounds__(256) void gather1_kernel(const int* __restrict__ rowptr,
                                                      const int* __restrict__ col,
                                                      const float* __restrict__ s,
                                                      const float* __restrict__ t,
                                                      const float* __restrict__ cptr,
                                                      const float* __restrict__ bptr,
                                                      float* __restrict__ h) {
  const int lane = threadIdx.x & 7;
  const int sub = threadIdx.x >> 3;
  const int n = blockIdx.x * 32 + sub;
  if (n >= NNODES) return;
  float4 c4 = *(const float4*)cptr;
  float mxc = fmaxf(fmaxf(c4.x, c4.y), fmaxf(c4.z, c4.w));
  float4 qs = make_float4(__expf(c4.x - mxc), __expf(c4.y - mxc),
                          __expf(c4.z - mxc), __expf(c4.w - mxc));
  float sinv = 1.f / (qs.x + qs.y + qs.z + qs.w);
  qs.x *= sinv; qs.y *= sinv; qs.z *= sinv; qs.w *= sinv;
  float4 sd = *(const float4*)(s + 4 * (size_t)n);
  const float4* trow = (const float4*)(t + (size_t)n * 64);
  float acc0 = dot4(qs, trow[2 * lane + 0]);
  float acc1 = dot4(qs, trow[2 * lane + 1]);
  const int beg = rowptr[n], end = rowptr[n + 1];
  int idx = beg;
  for (; idx + 3 < end; idx += 4) {
    int s0 = col[idx], s1 = col[idx + 1], s2 = col[idx + 2], s3 = col[idx + 3];
    float4 a0 = *(const float4*)(s + 4 * (size_t)s0);
    float4 a1 = *(const float4*)(s + 4 * (size_t)s1);
    float4 a2 = *(const float4*)(s + 4 * (size_t)s2);
    float4 a3 = *(const float4*)(s + 4 * (size_t)s3);
    const float4* t0 = (const float4*)(t + (size_t)s0 * 64) + 2 * lane;
    const float4* t1 = (const float4*)(t + (size_t)s1 * 64) + 2 * lane;
    const float4* t2 = (const float4*)(t + (size_t)s2 * 64) + 2 * lane;
    const float4* t3 = (const float4*)(t + (size_t)s3 * 64) + 2 * lane;
    float4 u0 = t0[0], v0 = t0[1];
    float4 u1 = t1[0], v1 = t1[1];
    float4 u2 = t2[0], v2 = t2[1];
    float4 u3 = t3[0], v3 = t3[1];
    float4 q0 = softq(a0, sd, c4);
    float4 q1 = softq(a1, sd, c4);
    float4 q2 = softq(a2, sd, c4);
    float4 q3 = softq(a3, sd, c4);
    acc0 += dot4(q0, u0) + dot4(q1, u1) + dot4(q2, u2) + dot4(q3, u3);
    acc1 += dot4(q0, v0) + dot4(q1, v1) + dot4(q2, v2) + dot4(q3, v3);
  }
  for (; idx < end; ++idx) {
    int src = col[idx];
    float4 qv = softq(*(const float4*)(s + 4 * (size_t)src), sd, c4);
    const float4* tw = (const float4*)(t + (size_t)src * 64) + 2 * lane;
    acc0 += dot4(qv, tw[0]);
    acc1 += dot4(qv, tw[1]);
  }
  float d = 1.f / (float)(end - beg + 1);
  h[(size_t)n * 16 + 2 * lane + 0] = fmaxf(acc0 * d + bptr[2 * lane + 0], 0.f);
  h[(size_t)n * 16 + 2 * lane + 1] = fmaxf(acc1 * d + bptr[2 * lane + 1], 0.f);
}

// ---------------- BN batch-stats over h3 [N,64] ----------------
__global__ __launch_bounds__(256) void stats_kernel(const float* __restrict__ h3,
                                                    float* __restrict__ sums) {
  const int o = threadIdx.x & 63;
  const int r = threadIdx.x >> 6;
  float accS = 0.f, accQ = 0.f;
  for (int base = blockIdx.x * 4; base < NNODES; base += gridDim.x * 4) {
    int n = base + r;
    if (n < NNODES) {
      float v = h3[(size_t)n * 64 + o];
      accS += v;
      accQ += v * v;
    }
  }
  __shared__ float ls[256], lq[256];
  ls[threadIdx.x] = accS;
  lq[threadIdx.x] = accQ;
  __syncthreads();
  if (threadIdx.x < 64) {
    float a = ls[threadIdx.x] + ls[threadIdx.x + 64] + ls[threadIdx.x + 128] + ls[threadIdx.x + 192];
    float qq = lq[threadIdx.x] + lq[threadIdx.x + 64] + lq[threadIdx.x + 128] + lq[threadIdx.x + 192];
    atomicAdd(&sums[threadIdx.x], a);
    atomicAdd(&sums[64 + threadIdx.x], qq);
  }
}

// ---------------- BN + MLP head + sigmoid, one thread per node ----------------
__global__ __launch_bounds__(256) void mlp_kernel(
    const float* __restrict__ h3, const float* __restrict__ sums,
    const float* __restrict__ gamma, const float* __restrict__ beta,
    const float* __restrict__ lw1, const float* __restrict__ lb1,
    const float* __restrict__ lw2, const float* __restrict__ lb2,
    const float* __restrict__ lw3, const float* __restrict__ lb3,
    const float* __restrict__ lw4, const float* __restrict__ lb4,
    const float* __restrict__ ow, const float* __restrict__ ob,
    float* __restrict__ out) {
  __shared__ float w1[64 * 32], w2[32 * 16], w3[16 * 8], w4[8 * 4];
  __shared__ float b1s[32], b2s[16], b3s[8], b4s[4], wos[4];
  __shared__ float scale[64], shift[64];
  int tid = threadIdx.x;
  for (int i = tid; i < 64 * 32; i += 256) w1[i] = lw1[i];
  for (int i = tid; i < 32 * 16; i += 256) w2[i] = lw2[i];
  if (tid < 128) w3[tid] = lw3[tid];
  if (tid < 32) { w4[tid] = lw4[tid]; b1s[tid] = lb1[tid]; }
  if (tid < 16) b2s[tid] = lb2[tid];
  if (tid < 8) b3s[tid] = lb3[tid];
  if (tid < 4) { b4s[tid] = lb4[tid]; wos[tid] = ow[tid]; }
  if (tid < 64) {
    float mu = sums[tid] * (1.f / NNODES);
    float var = sums[64 + tid] * (1.f / NNODES) - mu * mu;
    float sc = rsqrtf(var + 1e-5f) * gamma[tid];
    scale[tid] = sc;
    shift[tid] = beta[tid] - mu * sc;
  }
  __syncthreads();
  int n = blockIdx.x * 256 + tid;
  if (n >= NNODES) return;
  float obv = ob[0];
  const float4* hr = (const float4*)(h3 + (size_t)n * 64);
  float z1[32];
#pragma unroll
  for (int j = 0; j < 32; ++j) z1[j] = b1s[j];
  for (int i4 = 0; i4 < 16; ++i4) {
    float4 hv = hr[i4];
    float a0 = hv.x * scale[4 * i4 + 0] + shift[4 * i4 + 0];
    float a1 = hv.y * scale[4 * i4 + 1] + shift[4 * i4 + 1];
    float a2 = hv.z * scale[4 * i4 + 2] + shift[4 * i4 + 2];
    float a3 = hv.w * scale[4 * i4 + 3] + shift[4 * i4 + 3];
#pragma unroll
    for (int j = 0; j < 32; ++j) {
      z1[j] += a0 * w1[(4 * i4 + 0) * 32 + j] + a1 * w1[(4 * i4 + 1) * 32 + j] +
               a2 * w1[(4 * i4 + 2) * 32 + j] + a3 * w1[(4 * i4 + 3) * 32 + j];
    }
  }
  float z2[16];
#pragma unroll
  for (int j = 0; j < 16; ++j) z2[j] = b2s[j];
  for (int i = 0; i < 32; ++i) {
    float a = fmaxf(z1[i], 0.f);
#pragma unroll
    for (int j = 0; j < 16; ++j) z2[j] += a * w2[i * 16 + j];
  }
  float z3[8];
#pragma unroll
  for (int j = 0; j < 8; ++j) z3[j] = b3s[j];
  for (int i = 0; i < 16; ++i) {
    float a = fmaxf(z2[i], 0.f);
#pragma unroll
    for (int j = 0; j < 8; ++j) z3[j] += a * w3[i * 8 + j];
  }
  float z4[4];
#pragma unroll
  for (int j = 0; j < 4; ++j) z4[j] = b4s[j];
  for (int i = 0; i < 8; ++i) {
    float a = fmaxf(z3[i], 0.f);
#pragma unroll
    for (int j = 0; j < 4; ++j) z4[j] += a * w4[i * 4 + j];
  }
  float zo = obv;
#pragma unroll
  for (int i = 0; i < 4; ++i) zo += fmaxf(z4[i], 0.f) * wos[i];
  out[n] = 1.f / (1.f + __expf(-zo));
}

extern "C" void kernel_launch(void* const* d_in, const int* in_sizes, int n_in,
                              void* d_out, int out_size, void* d_ws, size_t ws_size,
                              hipStream_t stream) {
  const float* x  = (const float*)d_in[0];
  const int*   ei = (const int*)d_in[1];
  const float* W1 = (const float*)d_in[2];  const float* u1 = (const float*)d_in[3];
  const float* c1 = (const float*)d_in[4];  const float* b1 = (const float*)d_in[5];
  const float* W2 = (const float*)d_in[6];  const float* u2 = (const float*)d_in[7];
  const float* c2 = (const float*)d_in[8];  const float* b2 = (const float*)d_in[9];
  const float* W3 = (const float*)d_in[10]; const float* u3 = (const float*)d_in[11];
  const float* c3 = (const float*)d_in[12]; const float* b3 = (const float*)d_in[13];
  const float* gamma = (const float*)d_in[14]; const float* beta = (const float*)d_in[15];
  const float* lw1 = (const float*)d_in[16]; const float* lb1 = (const float*)d_in[17];
  const float* lw2 = (const float*)d_in[18]; const float* lb2 = (const float*)d_in[19];
  const float* lw3 = (const float*)d_in[20]; const float* lb3 = (const float*)d_in[21];
  const float* lw4 = (const float*)d_in[22]; const float* lb4 = (const float*)d_in[23];
  const float* ow  = (const float*)d_in[24]; const float* ob  = (const float*)d_in[25];
  float* out = (float*)d_out;

  float* t    = (float*)d_ws;                         // N*64   (layer-1 t)
  float* hA   = t + (size_t)NNODES * 64;              // N*64
  float* hB   = hA + (size_t)NNODES * 64;             // N*64
  float* s    = hB + (size_t)NNODES * 64;             // N*4
  float* sums = s + (size_t)NNODES * 4;               // 128
  float* Wk1  = sums + 128;                           // 4096
  float* Wk2  = Wk1 + 4096;                           // 2048
  float* Wk3  = Wk2 + 2048;                           // 8192
  int*   rowptr   = (int*)(Wk3 + 8192);               // N+1 (pad 8)
  int*   counts   = rowptr + NNODES + 8;              // N
  int*   blockSum = counts + NNODES;                  // 256
  int*   blockOff = blockSum + 256;                   // 256
  int*   col      = blockOff + 256;                   // E
  int*   rank     = col + NEDGES;                     // E

  hipMemsetAsync(counts, 0, NNODES * sizeof(int), stream);
  hipMemsetAsync(sums, 0, 128 * sizeof(float), stream);

  // ---- W transposes + CSR by dst ----
  prep_kernel<<<56, 256, 0, stream>>>(W1, W2, W3, Wk1, Wk2, Wk3);
  hist_kernel<<<(NEDGES + 255) / 256, 256, 0, stream>>>(ei, counts, rank);
  scanA_kernel<<<SCAN_BLOCKS, 256, 0, stream>>>(counts, rowptr, blockSum);
  scanB_kernel<<<1, 256, 0, stream>>>(blockSum, blockOff);
  scanC_kernel<<<SCAN_BLOCKS, 256, 0, stream>>>(rowptr, blockOff);
  scatter_kernel<<<NSLICE * 8, 256, 0, stream>>>(ei, rowptr, rank, col);

  // ---- layer 1: 64 -> 16 (t-gather, fused softmax) ----
  ngemm_kernel<64, 64, 16, false><<<(NNODES + 63) / 64, 256, 0, stream>>>(x, Wk1, nullptr, nullptr, t);
  s_kernel<64><<<(NNODES * 4 + 255) / 256, 256, 0, stream>>>(x, u1, s);
  gather1_kernel<<<(NNODES + 31) / 32, 256, 0, stream>>>(rowptr, col, s, t, c1, b1, hA);

  // ---- layer 2: 16 -> 32 (fused gather+transform) ----
  s_kernel<16><<<(NNODES * 4 + 255) / 256, 256, 0, stream>>>(hA, u2, s);
  fusedG_kernel<16, 32, 16><<<(NNODES + 127) / 128, 256, 0, stream>>>(rowptr, col, s, hA, Wk2, c2, b2, hB);

  // ---- layer 3: 32 -> 64 (fused gather+transform) ----
  s_kernel<32><<<(NNODES * 4 + 255) / 256, 256, 0, stream>>>(hB, u3, s);
  fusedG_kernel<32, 64, 16><<<(NNODES + 63) / 64, 256, 0, stream>>>(rowptr, col, s, hB, Wk3, c3, b3, hA);

  // ---- BN stats + MLP head ----
  stats_kernel<<<256, 256, 0, stream>>>(hA, sums);
  mlp_kernel<<<(NNODES + 255) / 256, 256, 0, stream>>>(hA, sums, gamma, beta, lw1, lb1,
                                                       lw2, lb2, lw3, lb3, lw4, lb4,
                                                       ow, ob, out);
}

// Round 15
// 242.081 us; speedup vs baseline: 1.1983x; 1.0135x over previous
//
#include <hip/hip_runtime.h>

#define NNODES 50000
#define NEDGES 800000
#define SCAN_BLOCKS ((NNODES + 255) / 256)   // 196
#define NPART (NNODES / 8)                   // 6250 nodes per XCD partition
#define EPS 2048                             // edges per slice
#define NSLICE ((NEDGES + EPS - 1) / EPS)    // 391

// per-edge attention weights: softmax over heads of (s_src - s_dst + c)
__device__ __forceinline__ float4 softq(float4 ss, float4 sd, float4 c4) {
  float l0 = ss.x - sd.x + c4.x;
  float l1 = ss.y - sd.y + c4.y;
  float l2 = ss.z - sd.z + c4.z;
  float l3 = ss.w - sd.w + c4.w;
  float mx = fmaxf(fmaxf(l0, l1), fmaxf(l2, l3));
  float e0 = __expf(l0 - mx), e1 = __expf(l1 - mx);
  float e2 = __expf(l2 - mx), e3 = __expf(l3 - mx);
  float inv = 1.f / (e0 + e1 + e2 + e3);
  return make_float4(e0 * inv, e1 * inv, e2 * inv, e3 * inv);
}

__device__ __forceinline__ void fma4(float4& a, float q, float4 v) {
  a.x += q * v.x; a.y += q * v.y; a.z += q * v.z; a.w += q * v.w;
}
__device__ __forceinline__ float dot4(float4 a, float4 b) {
  return a.x * b.x + a.y * b.y + a.z * b.z + a.w * b.w;
}
// store float4 to 4 consecutive-k slots of ldsT[k][nl]
__device__ __forceinline__ void st4T(float* ldsT, int k0, int NBp, int nl, float4 v) {
  ldsT[(k0 + 0) * NBp + nl] = v.x;
  ldsT[(k0 + 1) * NBp + nl] = v.y;
  ldsT[(k0 + 2) * NBp + nl] = v.z;
  ldsT[(k0 + 3) * NBp + nl] = v.w;
}
__device__ __forceinline__ float4 shfl4(float4 v, int e, int w) {
  return make_float4(__shfl(v.x, e, w), __shfl(v.y, e, w),
                     __shfl(v.z, e, w), __shfl(v.w, e, w));
}

// ---------------- CSR build: histogram over dst + per-edge rank ----------------
__global__ __launch_bounds__(256) void hist_kernel(const int* __restrict__ ei,
                                                   int* __restrict__ counts,
                                                   int* __restrict__ rank) {
  int e = blockIdx.x * 256 + threadIdx.x;
  if (e < NEDGES) rank[e] = atomicAdd(&counts[ei[NEDGES + e]], 1);
}

__global__ __launch_bounds__(256) void scanA_kernel(const int* __restrict__ counts,
                                                    int* __restrict__ rowptr,
                                                    int* __restrict__ blockSum) {
  __shared__ int sm[256];
  int i = blockIdx.x * 256 + threadIdx.x;
  int v = (i < NNODES) ? counts[i] : 0;
  sm[threadIdx.x] = v;
  __syncthreads();
  for (int off = 1; off < 256; off <<= 1) {
    int x = (threadIdx.x >= off) ? sm[threadIdx.x - off] : 0;
    __syncthreads();
    sm[threadIdx.x] += x;
    __syncthreads();
  }
  if (i < NNODES) rowptr[i] = sm[threadIdx.x] - v;
  if (threadIdx.x == 255) blockSum[blockIdx.x] = sm[255];
}

__global__ __launch_bounds__(256) void scanB_kernel(int* __restrict__ blockSum,
                                                    int* __restrict__ blockOff) {
  __shared__ int sm[256];
  int v = (threadIdx.x < SCAN_BLOCKS) ? blockSum[threadIdx.x] : 0;
  sm[threadIdx.x] = v;
  __syncthreads();
  for (int off = 1; off < 256; off <<= 1) {
    int x = (threadIdx.x >= off) ? sm[threadIdx.x - off] : 0;
    __syncthreads();
    sm[threadIdx.x] += x;
    __syncthreads();
  }
  if (threadIdx.x < SCAN_BLOCKS) blockOff[threadIdx.x] = sm[threadIdx.x] - v;
}

__global__ __launch_bounds__(256) void scanC_kernel(int* __restrict__ rowptr,
                                                    const int* __restrict__ blockOff) {
  int i = blockIdx.x * 256 + threadIdx.x;
  if (i < NNODES) rowptr[i] += blockOff[blockIdx.x];
  if (i == 0) rowptr[NNODES] = NEDGES;
}

// Atomic-free XCD-partitioned scatter.
__global__ __launch_bounds__(256) void scatter_kernel(const int* __restrict__ ei,
                                                      const int* __restrict__ rowptr,
                                                      const int* __restrict__ rank,
                                                      int* __restrict__ col) {
  const int p = blockIdx.x & 7;
  const int sl = blockIdx.x >> 3;
  const int P0 = p * NPART;
  const int e1 = min((sl + 1) * EPS, NEDGES);
  for (int e = sl * EPS + threadIdx.x; e < e1; e += 256) {
    int dst = __builtin_nontemporal_load(&ei[NEDGES + e]);
    if ((unsigned)(dst - P0) < (unsigned)NPART) {
      int pos = rowptr[dst] + __builtin_nontemporal_load(&rank[e]);
      col[pos] = __builtin_nontemporal_load(&ei[e]);
    }
  }
}

// ---------------- W pre-transpose into [k][o] rows (scalar-load friendly) ----
__global__ __launch_bounds__(256) void prep_kernel(const float* __restrict__ W1,
                                                   const float* __restrict__ W2,
                                                   const float* __restrict__ W3,
                                                   float* __restrict__ Wk1,
                                                   float* __restrict__ Wk2,
                                                   float* __restrict__ Wk3) {
  int i = blockIdx.x * 256 + threadIdx.x;
  if (i < 4096) {
    int f = i >> 6, j = i & 63;
    Wk1[i] = W1[f * 64 + ((j & 3) << 4) + (j >> 2)];
  } else if (i < 6144) {
    int i2 = i - 4096;
    int k = i2 >> 5, o = i2 & 31;
    int hh = k >> 4, f = k & 15;
    Wk2[i2] = W2[f * 128 + hh * 32 + o];
  } else if (i < 14336) {
    int i3 = i - 6144;
    int k = i3 >> 6, o = i3 & 63;
    int hh = k >> 5, f = k & 31;
    Wk3[i3] = W3[f * 256 + hh * 64 + o];
  }
}

// ---------------- layer-1 t GEMM: t[n][j] = x[n][:64] . Wk1[j][:64] ----------
template<int K, int OUTT, int MO, bool DEGBIAS>
__global__ __launch_bounds__(256) void ngemm_kernel(const float* __restrict__ A,
                                                    const float* __restrict__ Wk,
                                                    const int* __restrict__ rowptr,
                                                    const float* __restrict__ bptr,
                                                    float* __restrict__ C) {
  constexpr int OG = OUTT / MO;
  constexpr int NB = 256 / OG;
  constexpr int NBp = NB + 1;
  __shared__ float ldsT[K * NBp];
  const int tid = threadIdx.x;
  const int nb0 = blockIdx.x * NB;
  for (int i = tid; i < NB * (K / 4); i += 256) {
    int r = i / (K / 4), kq = i - r * (K / 4);
    int n = nb0 + r;
    if (n >= NNODES) n = NNODES - 1;
    float4 v = ((const float4*)A)[n * (K / 4) + kq];
    st4T(ldsT, kq << 2, NBp, r, v);
  }
  __syncthreads();
  const int o0 = __builtin_amdgcn_readfirstlane(tid / NB) * MO;
  const int nl = tid & (NB - 1);
  const int n = nb0 + nl;
  float acc[MO];
#pragma unroll
  for (int m = 0; m < MO; ++m) acc[m] = 0.f;
#pragma unroll 4
  for (int k = 0; k < K; ++k) {
    float a = ldsT[k * NBp + nl];
    const float* wr = Wk + k * OUTT + o0;   // wave-uniform -> s_load
#pragma unroll
    for (int m = 0; m < MO; ++m) acc[m] += a * wr[m];
  }
  if (n < NNODES) {
    float sc = 1.f;
    if (DEGBIAS) sc = 1.f / (float)(rowptr[n + 1] - rowptr[n] + 1);
#pragma unroll
    for (int m4 = 0; m4 < MO / 4; ++m4) {
      float4 v;
      if (DEGBIAS) {
        v.x = fmaxf(acc[m4 * 4 + 0] * sc + bptr[o0 + m4 * 4 + 0], 0.f);
        v.y = fmaxf(acc[m4 * 4 + 1] * sc + bptr[o0 + m4 * 4 + 1], 0.f);
        v.z = fmaxf(acc[m4 * 4 + 2] * sc + bptr[o0 + m4 * 4 + 2], 0.f);
        v.w = fmaxf(acc[m4 * 4 + 3] * sc + bptr[o0 + m4 * 4 + 3], 0.f);
      } else {
        v = make_float4(acc[m4 * 4 + 0], acc[m4 * 4 + 1],
                        acc[m4 * 4 + 2], acc[m4 * 4 + 3]);
      }
      ((float4*)C)[n * (OUTT / 4) + (o0 >> 2) + m4] = v;
    }
  }
}

// ---------------- fused g-gather + transform (layers 2/3) ----------------
// Phase 1: gather with fused softmax; per LPN-edge batch, lane j computes the
// softmax of edge j only (coalesced col load) and broadcasts q via shfl (DS
// pipe). Accumulators written straight into the transposed LDS tile ldsT[k][n].
// Phase 2: ngemm loop (1 ds_read + MO FMA per k, W via s_load), /deg+bias+relu.
template<int FIN, int OUTT, int MO>
__global__ __launch_bounds__(256) void fusedG_kernel(const int* __restrict__ rowptr,
                                                     const int* __restrict__ col,
                                                     const float* __restrict__ s,
                                                     const float* __restrict__ x,
                                                     const float* __restrict__ Wk,
                                                     const float* __restrict__ cptr,
                                                     const float* __restrict__ bptr,
                                                     float* __restrict__ h) {
  constexpr int LPN = FIN / 8;        // lanes per node (2 or 4)
  constexpr int NB = 256 / LPN;       // nodes per block (128 or 64)
  constexpr int NBp = NB + 1;
  constexpr int K = 4 * FIN;
  constexpr int OG = OUTT / MO;       // must equal 256/NB (wave-uniform o0)
  static_assert(OG == 256 / NB, "geometry mismatch");
  __shared__ float ldsT[K * NBp];
  const int tid = threadIdx.x;
  const int nb0 = blockIdx.x * NB;
  const float4* sF4 = (const float4*)s;
  const float4* xF4 = (const float4*)x;

  // ---- phase 1: gather ----
  {
    const int lane = tid & (LPN - 1);
    const int sub = tid / LPN;
    int n = nb0 + sub;
    if (n >= NNODES) n = NNODES - 1;   // duplicate work, discarded in phase 2
    float4 c4 = *(const float4*)cptr;
    float mxc = fmaxf(fmaxf(c4.x, c4.y), fmaxf(c4.z, c4.w));
    float4 qsl = make_float4(__expf(c4.x - mxc), __expf(c4.y - mxc),
                             __expf(c4.z - mxc), __expf(c4.w - mxc));
    float sinv = 1.f / (qsl.x + qsl.y + qsl.z + qsl.w);
    qsl.x *= sinv; qsl.y *= sinv; qsl.z *= sinv; qsl.w *= sinv;
    float4 sd = sF4[n];
    const float4* xn = xF4 + n * (FIN / 4) + 2 * lane;
    float4 xa = xn[0], xb = xn[1];
    float4 g0a = make_float4(qsl.x * xa.x, qsl.x * xa.y, qsl.x * xa.z, qsl.x * xa.w);
    float4 g0b = make_float4(qsl.x * xb.x, qsl.x * xb.y, qsl.x * xb.z, qsl.x * xb.w);
    float4 g1a = make_float4(qsl.y * xa.x, qsl.y * xa.y, qsl.y * xa.z, qsl.y * xa.w);
    float4 g1b = make_float4(qsl.y * xb.x, qsl.y * xb.y, qsl.y * xb.z, qsl.y * xb.w);
    float4 g2a = make_float4(qsl.z * xa.x, qsl.z * xa.y, qsl.z * xa.z, qsl.z * xa.w);
    float4 g2b = make_float4(qsl.z * xb.x, qsl.z * xb.y, qsl.z * xb.z, qsl.z * xb.w);
    float4 g3a = make_float4(qsl.w * xa.x, qsl.w * xa.y, qsl.w * xa.z, qsl.w * xa.w);
    float4 g3b = make_float4(qsl.w * xb.x, qsl.w * xb.y, qsl.w * xb.z, qsl.w * xb.w);
    const int beg = rowptr[n], end = rowptr[n + 1];
    int idx = beg;
    for (; idx + LPN <= end; idx += LPN) {
      int myS = col[idx + lane];                 // per-lane coalesced
      float4 qL = softq(sF4[myS], sd, c4);       // one softmax per lane
#pragma unroll
      for (int e = 0; e < LPN; ++e) {
        int srcE = __shfl(myS, e, LPN);
        float4 q = shfl4(qL, e, LPN);
        const float4* xr = xF4 + srcE * (FIN / 4) + 2 * lane;
        float4 x0a = xr[0], x0b = xr[1];
        fma4(g0a, q.x, x0a); fma4(g0b, q.x, x0b);
        fma4(g1a, q.y, x0a); fma4(g1b, q.y, x0b);
        fma4(g2a, q.z, x0a); fma4(g2b, q.z, x0b);
        fma4(g3a, q.w, x0a); fma4(g3b, q.w, x0b);
      }
    }
    for (; idx < end; ++idx) {
      int s0 = col[idx];
      float4 qv = softq(sF4[s0], sd, c4);
      const float4* xr = xF4 + s0 * (FIN / 4) + 2 * lane;
      float4 x0a = xr[0], x0b = xr[1];
      fma4(g0a, qv.x, x0a); fma4(g0b, qv.x, x0b);
      fma4(g1a, qv.y, x0a); fma4(g1b, qv.y, x0b);
      fma4(g2a, qv.z, x0a); fma4(g2b, qv.z, x0b);
      fma4(g3a, qv.w, x0a); fma4(g3b, qv.w, x0b);
    }
    // write to transposed tile: k = hh*FIN + 8*lane + j
    const int f0 = 8 * lane;
    st4T(ldsT, 0 * FIN + f0, NBp, sub, g0a); st4T(ldsT, 0 * FIN + f0 + 4, NBp, sub, g0b);
    st4T(ldsT, 1 * FIN + f0, NBp, sub, g1a); st4T(ldsT, 1 * FIN + f0 + 4, NBp, sub, g1b);
    st4T(ldsT, 2 * FIN + f0, NBp, sub, g2a); st4T(ldsT, 2 * FIN + f0 + 4, NBp, sub, g2b);
    st4T(ldsT, 3 * FIN + f0, NBp, sub, g3a); st4T(ldsT, 3 * FIN + f0 + 4, NBp, sub, g3b);
  }
  __syncthreads();

  // ---- phase 2: transform ----
  const int o0 = __builtin_amdgcn_readfirstlane(tid / NB) * MO;
  const int nl = tid & (NB - 1);
  const int n = nb0 + nl;
  float acc[MO];
#pragma unroll
  for (int m = 0; m < MO; ++m) acc[m] = 0.f;
#pragma unroll 4
  for (int k = 0; k < K; ++k) {
    float a = ldsT[k * NBp + nl];
    const float* wr = Wk + k * OUTT + o0;   // wave-uniform -> s_load
#pragma unroll
    for (int m = 0; m < MO; ++m) acc[m] += a * wr[m];
  }
  if (n < NNODES) {
    float sc = 1.f / (float)(rowptr[n + 1] - rowptr[n] + 1);
#pragma unroll
    for (int m4 = 0; m4 < MO / 4; ++m4) {
      float4 v;
      v.x = fmaxf(acc[m4 * 4 + 0] * sc + bptr[o0 + m4 * 4 + 0], 0.f);
      v.y = fmaxf(acc[m4 * 4 + 1] * sc + bptr[o0 + m4 * 4 + 1], 0.f);
      v.z = fmaxf(acc[m4 * 4 + 2] * sc + bptr[o0 + m4 * 4 + 2], 0.f);
      v.w = fmaxf(acc[m4 * 4 + 3] * sc + bptr[o0 + m4 * 4 + 3], 0.f);
      ((float4*)h)[n * (OUTT / 4) + (o0 >> 2) + m4] = v;
    }
  }
}

// ---------------- s = x @ u  ([N,4]) ----------------
template<int FIN>
__global__ __launch_bounds__(256) void s_kernel(const float* __restrict__ x,
                                                const float* __restrict__ u,
                                                float* __restrict__ s) {
  int tid = blockIdx.x * 256 + threadIdx.x;
  int n = tid >> 2, h = tid & 3;
  if (n >= NNODES) return;
  const float4* xr = (const float4*)x + n * (FIN / 4);
  float acc = 0.f;
#pragma unroll
  for (int f4 = 0; f4 < FIN / 4; ++f4) {
    float4 xv = xr[f4];
    acc += xv.x * u[(4 * f4 + 0) * 4 + h] + xv.y * u[(4 * f4 + 1) * 4 + h] +
           xv.z * u[(4 * f4 + 2) * 4 + h] + xv.w * u[(4 * f4 + 3) * 4 + h];
  }
  s[tid] = acc;  // tid == n*4+h
}

// ---------------- layer-1 gather over t, fused softmax + shfl dedup ----------
// 8 lanes/node; per 8-edge batch lane j computes softmax of edge j, broadcasts
// q/src via width-8 shfl; each lane accumulates outputs o=2*lane, 2*lane+1.
__global__ __launch_bounds__(256) void gather1_kernel(const int* __restrict__ rowptr,
                                                      const int* __restrict__ col,
                                                      const float* __restrict__ s,
                                                      const float* __restrict__ t,
                                                      const float* __restrict__ cptr,
                                                      const float* __restrict__ bptr,
                                                      float* __restrict__ h) {
  const int lane = threadIdx.x & 7;
  const int sub = threadIdx.x >> 3;
  const int n = blockIdx.x * 32 + sub;
  if (n >= NNODES) return;
  const float4* sF4 = (const float4*)s;
  const float4* tF4 = (const float4*)t;
  float4 c4 = *(const float4*)cptr;
  float mxc = fmaxf(fmaxf(c4.x, c4.y), fmaxf(c4.z, c4.w));
  float4 qs = make_float4(__expf(c4.x - mxc), __expf(c4.y - mxc),
                          __expf(c4.z - mxc), __expf(c4.w - mxc));
  float sinv = 1.f / (qs.x + qs.y + qs.z + qs.w);
  qs.x *= sinv; qs.y *= sinv; qs.z *= sinv; qs.w *= sinv;
  float4 sd = sF4[n];
  const float4* trow = tF4 + n * 16 + 2 * lane;
  float acc0 = dot4(qs, trow[0]);
  float acc1 = dot4(qs, trow[1]);
  const int beg = rowptr[n], end = rowptr[n + 1];
  int idx = beg;
  for (; idx + 8 <= end; idx += 8) {
    int myS = col[idx + lane];                 // per-lane coalesced
    float4 qL = softq(sF4[myS], sd, c4);       // one softmax per lane
#pragma unroll
    for (int e = 0; e < 8; ++e) {
      int srcE = __shfl(myS, e, 8);
      float4 q = shfl4(qL, e, 8);
      const float4* tw = tF4 + srcE * 16 + 2 * lane;
      acc0 += dot4(q, tw[0]);
      acc1 += dot4(q, tw[1]);
    }
  }
  for (; idx < end; ++idx) {
    int src = col[idx];
    float4 qv = softq(sF4[src], sd, c4);
    const float4* tw = tF4 + src * 16 + 2 * lane;
    acc0 += dot4(qv, tw[0]);
    acc1 += dot4(qv, tw[1]);
  }
  float d = 1.f / (float)(end - beg + 1);
  h[n * 16 + 2 * lane + 0] = fmaxf(acc0 * d + bptr[2 * lane + 0], 0.f);
  h[n * 16 + 2 * lane + 1] = fmaxf(acc1 * d + bptr[2 * lane + 1], 0.f);
}

// ---------------- BN batch-stats over h3 [N,64] ----------------
__global__ __launch_bounds__(256) void stats_kernel(const float* __restrict__ h3,
                                                    float* __restrict__ sums) {
  const int o = threadIdx.x & 63;
  const int r = threadIdx.x >> 6;
  float accS = 0.f, accQ = 0.f;
  for (int base = blockIdx.x * 4; base < NNODES; base += gridDim.x * 4) {
    int n = base + r;
    if (n < NNODES) {
      float v = h3[n * 64 + o];
      accS += v;
      accQ += v * v;
    }
  }
  __shared__ float ls[256], lq[256];
  ls[threadIdx.x] = accS;
  lq[threadIdx.x] = accQ;
  __syncthreads();
  if (threadIdx.x < 64) {
    float a = ls[threadIdx.x] + ls[threadIdx.x + 64] + ls[threadIdx.x + 128] + ls[threadIdx.x + 192];
    float qq = lq[threadIdx.x] + lq[threadIdx.x + 64] + lq[threadIdx.x + 128] + lq[threadIdx.x + 192];
    atomicAdd(&sums[threadIdx.x], a);
    atomicAdd(&sums[64 + threadIdx.x], qq);
  }
}

// ---------------- BN + MLP head + sigmoid, one thread per node ----------------
__global__ __launch_bounds__(256) void mlp_kernel(
    const float* __restrict__ h3, const float* __restrict__ sums,
    const float* __restrict__ gamma, const float* __restrict__ beta,
    const float* __restrict__ lw1, const float* __restrict__ lb1,
    const float* __restrict__ lw2, const float* __restrict__ lb2,
    const float* __restrict__ lw3, const float* __restrict__ lb3,
    const float* __restrict__ lw4, const float* __restrict__ lb4,
    const float* __restrict__ ow, const float* __restrict__ ob,
    float* __restrict__ out) {
  __shared__ float w1[64 * 32], w2[32 * 16], w3[16 * 8], w4[8 * 4];
  __shared__ float b1s[32], b2s[16], b3s[8], b4s[4], wos[4];
  __shared__ float scale[64], shift[64];
  int tid = threadIdx.x;
  for (int i = tid; i < 64 * 32; i += 256) w1[i] = lw1[i];
  for (int i = tid; i < 32 * 16; i += 256) w2[i] = lw2[i];
  if (tid < 128) w3[tid] = lw3[tid];
  if (tid < 32) { w4[tid] = lw4[tid]; b1s[tid] = lb1[tid]; }
  if (tid < 16) b2s[tid] = lb2[tid];
  if (tid < 8) b3s[tid] = lb3[tid];
  if (tid < 4) { b4s[tid] = lb4[tid]; wos[tid] = ow[tid]; }
  if (tid < 64) {
    float mu = sums[tid] * (1.f / NNODES);
    float var = sums[64 + tid] * (1.f / NNODES) - mu * mu;
    float sc = rsqrtf(var + 1e-5f) * gamma[tid];
    scale[tid] = sc;
    shift[tid] = beta[tid] - mu * sc;
  }
  __syncthreads();
  int n = blockIdx.x * 256 + tid;
  if (n >= NNODES) return;
  float obv = ob[0];
  const float4* hr = (const float4*)h3 + n * 16;
  float z1[32];
#pragma unroll
  for (int j = 0; j < 32; ++j) z1[j] = b1s[j];
  for (int i4 = 0; i4 < 16; ++i4) {
    float4 hv = hr[i4];
    float a0 = hv.x * scale[4 * i4 + 0] + shift[4 * i4 + 0];
    float a1 = hv.y * scale[4 * i4 + 1] + shift[4 * i4 + 1];
    float a2 = hv.z * scale[4 * i4 + 2] + shift[4 * i4 + 2];
    float a3 = hv.w * scale[4 * i4 + 3] + shift[4 * i4 + 3];
#pragma unroll
    for (int j = 0; j < 32; ++j) {
      z1[j] += a0 * w1[(4 * i4 + 0) * 32 + j] + a1 * w1[(4 * i4 + 1) * 32 + j] +
               a2 * w1[(4 * i4 + 2) * 32 + j] + a3 * w1[(4 * i4 + 3) * 32 + j];
    }
  }
  float z2[16];
#pragma unroll
  for (int j = 0; j < 16; ++j) z2[j] = b2s[j];
  for (int i = 0; i < 32; ++i) {
    float a = fmaxf(z1[i], 0.f);
#pragma unroll
    for (int j = 0; j < 16; ++j) z2[j] += a * w2[i * 16 + j];
  }
  float z3[8];
#pragma unroll
  for (int j = 0; j < 8; ++j) z3[j] = b3s[j];
  for (int i = 0; i < 16; ++i) {
    float a = fmaxf(z2[i], 0.f);
#pragma unroll
    for (int j = 0; j < 8; ++j) z3[j] += a * w3[i * 8 + j];
  }
  float z4[4];
#pragma unroll
  for (int j = 0; j < 4; ++j) z4[j] = b4s[j];
  for (int i = 0; i < 8; ++i) {
    float a = fmaxf(z3[i], 0.f);
#pragma unroll
    for (int j = 0; j < 4; ++j) z4[j] += a * w4[i * 4 + j];
  }
  float zo = obv;
#pragma unroll
  for (int i = 0; i < 4; ++i) zo += fmaxf(z4[i], 0.f) * wos[i];
  out[n] = 1.f / (1.f + __expf(-zo));
}

extern "C" void kernel_launch(void* const* d_in, const int* in_sizes, int n_in,
                              void* d_out, int out_size, void* d_ws, size_t ws_size,
                              hipStream_t stream) {
  const float* x  = (const float*)d_in[0];
  const int*   ei = (const int*)d_in[1];
  const float* W1 = (const float*)d_in[2];  const float* u1 = (const float*)d_in[3];
  const float* c1 = (const float*)d_in[4];  const float* b1 = (const float*)d_in[5];
  const float* W2 = (const float*)d_in[6];  const float* u2 = (const float*)d_in[7];
  const float* c2 = (const float*)d_in[8];  const float* b2 = (const float*)d_in[9];
  const float* W3 = (const float*)d_in[10]; const float* u3 = (const float*)d_in[11];
  const float* c3 = (const float*)d_in[12]; const float* b3 = (const float*)d_in[13];
  const float* gamma = (const float*)d_in[14]; const float* beta = (const float*)d_in[15];
  const float* lw1 = (const float*)d_in[16]; const float* lb1 = (const float*)d_in[17];
  const float* lw2 = (const float*)d_in[18]; const float* lb2 = (const float*)d_in[19];
  const float* lw3 = (const float*)d_in[20]; const float* lb3 = (const float*)d_in[21];
  const float* lw4 = (const float*)d_in[22]; const float* lb4 = (const float*)d_in[23];
  const float* ow  = (const float*)d_in[24]; const float* ob  = (const float*)d_in[25];
  float* out = (float*)d_out;

  float* t    = (float*)d_ws;                         // N*64   (layer-1 t)
  float* hA   = t + (size_t)NNODES * 64;              // N*64
  float* hB   = hA + (size_t)NNODES * 64;             // N*64
  float* s    = hB + (size_t)NNODES * 64;             // N*4
  float* sums = s + (size_t)NNODES * 4;               // 128
  float* Wk1  = sums + 128;                           // 4096
  float* Wk2  = Wk1 + 4096;                           // 2048
  float* Wk3  = Wk2 + 2048;                           // 8192
  int*   rowptr   = (int*)(Wk3 + 8192);               // N+1 (pad 8)
  int*   counts   = rowptr + NNODES + 8;              // N
  int*   blockSum = counts + NNODES;                  // 256
  int*   blockOff = blockSum + 256;                   // 256
  int*   col      = blockOff + 256;                   // E
  int*   rank     = col + NEDGES;                     // E

  hipMemsetAsync(counts, 0, NNODES * sizeof(int), stream);
  hipMemsetAsync(sums, 0, 128 * sizeof(float), stream);

  // ---- W transposes + CSR by dst ----
  prep_kernel<<<56, 256, 0, stream>>>(W1, W2, W3, Wk1, Wk2, Wk3);
  hist_kernel<<<(NEDGES + 255) / 256, 256, 0, stream>>>(ei, counts, rank);
  scanA_kernel<<<SCAN_BLOCKS, 256, 0, stream>>>(counts, rowptr, blockSum);
  scanB_kernel<<<1, 256, 0, stream>>>(blockSum, blockOff);
  scanC_kernel<<<SCAN_BLOCKS, 256, 0, stream>>>(rowptr, blockOff);
  scatter_kernel<<<NSLICE * 8, 256, 0, stream>>>(ei, rowptr, rank, col);

  // ---- layer 1: 64 -> 16 (t-gather, fused softmax) ----
  ngemm_kernel<64, 64, 16, false><<<(NNODES + 63) / 64, 256, 0, stream>>>(x, Wk1, nullptr, nullptr, t);
  s_kernel<64><<<(NNODES * 4 + 255) / 256, 256, 0, stream>>>(x, u1, s);
  gather1_kernel<<<(NNODES + 31) / 32, 256, 0, stream>>>(rowptr, col, s, t, c1, b1, hA);

  // ---- layer 2: 16 -> 32 (fused gather+transform) ----
  s_kernel<16><<<(NNODES * 4 + 255) / 256, 256, 0, stream>>>(hA, u2, s);
  fusedG_kernel<16, 32, 16><<<(NNODES + 127) / 128, 256, 0, stream>>>(rowptr, col, s, hA, Wk2, c2, b2, hB);

  // ---- layer 3: 32 -> 64 (fused gather+transform) ----
  s_kernel<32><<<(NNODES * 4 + 255) / 256, 256, 0, stream>>>(hB, u3, s);
  fusedG_kernel<32, 64, 16><<<(NNODES + 63) / 64, 256, 0, stream>>>(rowptr, col, s, hB, Wk3, c3, b3, hA);

  // ---- BN stats + MLP head ----
  stats_kernel<<<256, 256, 0, stream>>>(hA, sums);
  mlp_kernel<<<(NNODES + 255) / 256, 256, 0, stream>>>(hA, sums, gamma, beta, lw1, lb1,
                                                       lw2, lb2, lw3, lb3, lw4, lb4,
                                                       ow, ob, out);
}